// Round 12
// baseline (643.172 us; speedup 1.0000x reference)
//
#include <hip/hip_runtime.h>

#define Hh 96
#define Ww 96
#define HW 9216
#define NPIX 589824   // 9216*64

typedef __attribute__((ext_vector_type(8))) short bf16x8;
typedef __attribute__((ext_vector_type(4))) float f32x4;

__device__ __forceinline__ unsigned short f2bf(float f) {
    unsigned int u = __float_as_uint(f);
    u += 0x7fff + ((u >> 16) & 1);          // RNE
    return (unsigned short)(u >> 16);
}

// ---------------------------------------------------------------------------
// Weight prep: fp32 OIHW -> bf16 [tap][oc][ICp] per conv, ICp zero-padded.
// ---------------------------------------------------------------------------
__global__ __launch_bounds__(256) void prep_w_k(
    const float* __restrict__ w0, const float* __restrict__ w1,
    const float* __restrict__ w2, const float* __restrict__ w3,
    const float* __restrict__ w4, const float* __restrict__ c2w,
    unsigned short* __restrict__ wb)
{
    int idx = blockIdx.x * 256 + threadIdx.x;
    const int DBSZ = 129024, TOT_DB = 12 * 129024;
    if (idx >= TOT_DB + 36864) return;
    float val;
    if (idx < TOT_DB) {
        int d = idx / DBSZ, rem = idx - d * DBSZ;
        int base, OC, IC, ICp; const float* wp;
        if      (rem < 9216)  { base = 0;     OC = 16; IC = 64;  ICp = 64;  wp = w0; }
        else if (rem < 23040) { base = 9216;  OC = 16; IC = 80;  ICp = 96;  wp = w1; }
        else if (rem < 36864) { base = 23040; OC = 16; IC = 96;  ICp = 96;  wp = w2; }
        else if (rem < 55296) { base = 36864; OC = 16; IC = 112; ICp = 128; wp = w3; }
        else                  { base = 55296; OC = 64; IC = 128; ICp = 128; wp = w4; }
        int e   = rem - base;
        int tap = e / (OC * ICp);
        int r   = e - tap * (OC * ICp);
        int oc  = r / ICp, icp = r - oc * ICp;
        val = (icp < IC) ? wp[(((size_t)d * OC + oc) * IC + icp) * 9 + tap] : 0.f;
    } else {
        int e = idx - TOT_DB;
        int tap = e / 4096, r = e & 4095;
        int oc = r >> 6, icp = r & 63;
        val = c2w[((size_t)(oc * 64 + icp)) * 9 + tap];
    }
    wb[idx] = f2bf(val);
}

// ---------------------------------------------------------------------------
// c1: 3->64 conv from NCHW fp32 x; writes x0f (fp32 NHWC) + dba (bf16 [9216][64])
// ---------------------------------------------------------------------------
__global__ __launch_bounds__(256) void c1_k(
    const float* __restrict__ x, const float* __restrict__ w,
    const float* __restrict__ bias,
    float* __restrict__ x0f, unsigned short* __restrict__ dba)
{
    __shared__ float sw[1728];
    __shared__ float sb[64];
    int tid = threadIdx.x;
    for (int i = tid; i < 1728; i += 256) sw[i] = w[i];
    if (tid < 64) sb[tid] = bias[tid];
    __syncthreads();
    int px = blockIdx.x * 256 + tid;
    int gy = px / 96, gx = px - (px / 96) * 96;
    float in[3][3][3];
    #pragma unroll
    for (int c = 0; c < 3; ++c)
        #pragma unroll
        for (int dy = 0; dy < 3; ++dy)
            #pragma unroll
            for (int dx = 0; dx < 3; ++dx) {
                int yy = gy - 1 + dy, xx = gx - 1 + dx;
                in[c][dy][dx] = (yy >= 0 && yy < 96 && xx >= 0 && xx < 96)
                                ? x[c * HW + yy * 96 + xx] : 0.f;
            }
    for (int oc = 0; oc < 64; ++oc) {
        float acc = sb[oc];
        const float* wp = &sw[oc * 27];
        #pragma unroll
        for (int c = 0; c < 3; ++c)
            #pragma unroll
            for (int dy = 0; dy < 3; ++dy)
                #pragma unroll
                for (int dx = 0; dx < 3; ++dx)
                    acc += wp[(c * 3 + dy) * 3 + dx] * in[c][dy][dx];
        x0f[(size_t)px * 64 + oc] = acc;
        dba[(size_t)px * 64 + oc] = f2bf(acc);
    }
}

// ---------------------------------------------------------------------------
// Fused dense block, R12: 4x4 out tile, halo 14x14 = 196 px, LDS 53.3 KB ->
// grid 576 blocks = TRUE 2 independent blocks/CU (R5-R11 had grid 288 ->
// 1 block/CU on 224 of 256 CUs; launch_bounds can't create blocks the grid
// doesn't supply). Independent blocks interleave stages -> latency overlap.
// ch 0..63 = h, 64..127 = growth outputs (cv1..cv4 at 64/80/96/112).
// Clamp-and-discard (no branches in MFMA loops). K-split chains where MX=1.
// ---------------------------------------------------------------------------
#define CSTR 136
#define RSTR 14   // region row stride in px

template<int NS, int BS, int ICP, int OCH, bool KSPLIT>
__device__ __forceinline__ void growth_stage(
    unsigned short* s, const unsigned short* __restrict__ wst,
    const float* __restrict__ bias, int wid, int l16, int q)
{
    constexpr int NPXr = NS * NS;
    constexpr int NT = (NPXr + 15) / 16;
    constexpr int MX = (NT + 3) / 4;
    constexpr int K1 = KSPLIT ? 64 : ICP;
    f32x4 accA[MX], accB[MX];
    int lp0[MX], outp[MX];
    bool ok[MX];
    #pragma unroll
    for (int i = 0; i < MX; ++i) {
        int nt = wid + i * 4;
        int p  = nt * 16 + l16;
        bool live = (nt < NT) && (p < NPXr);
        ok[i] = live;
        int pc = live ? p : 0;            // clamp: reads stay in-bounds
        int r = pc / NS, c = pc - (pc / NS) * NS;
        lp0[i]  = (BS - 1 + r) * RSTR + (BS - 1 + c);
        outp[i] = (BS + r) * RSTR + (BS + c);
        accA[i] = (f32x4){0.f, 0.f, 0.f, 0.f};
        accB[i] = (f32x4){0.f, 0.f, 0.f, 0.f};
    }
    #pragma unroll
    for (int kb = 0; kb < K1; kb += 32) {
        #pragma unroll
        for (int tap = 0; tap < 9; ++tap) {
            const int dy = tap / 3, dx = tap - dy * 3;
            bf16x8 a = *(const bf16x8*)&wst[(tap * 16 + l16) * ICP + kb + q * 8];
            #pragma unroll
            for (int i = 0; i < MX; ++i) {
                bf16x8 b = *(const bf16x8*)&s[(lp0[i] + dy * RSTR + dx) * CSTR + kb + q * 8];
                accA[i] = __builtin_amdgcn_mfma_f32_16x16x32_bf16(a, b, accA[i], 0, 0, 0);
            }
        }
    }
    #pragma unroll
    for (int kb = K1; kb < ICP; kb += 32) {
        #pragma unroll
        for (int tap = 0; tap < 9; ++tap) {
            const int dy = tap / 3, dx = tap - dy * 3;
            bf16x8 a = *(const bf16x8*)&wst[(tap * 16 + l16) * ICP + kb + q * 8];
            #pragma unroll
            for (int i = 0; i < MX; ++i) {
                bf16x8 b = *(const bf16x8*)&s[(lp0[i] + dy * RSTR + dx) * CSTR + kb + q * 8];
                accB[i] = __builtin_amdgcn_mfma_f32_16x16x32_bf16(a, b, accB[i], 0, 0, 0);
            }
        }
    }
    const float4 bv = *(const float4*)&bias[q * 4];
    #pragma unroll
    for (int i = 0; i < MX; ++i) {
        if (!ok[i]) continue;
        f32x4 acc = accA[i] + accB[i];
        float v0 = acc[0] + bv.x; v0 = v0 > 0.f ? v0 : 0.2f * v0;
        float v1 = acc[1] + bv.y; v1 = v1 > 0.f ? v1 : 0.2f * v1;
        float v2 = acc[2] + bv.z; v2 = v2 > 0.f ? v2 : 0.2f * v2;
        float v3 = acc[3] + bv.w; v3 = v3 > 0.f ? v3 : 0.2f * v3;
        ushort4 o = {f2bf(v0), f2bf(v1), f2bf(v2), f2bf(v3)};
        *(ushort4*)&s[outp[i] * CSTR + OCH + q * 4] = o;
    }
}

__global__ __launch_bounds__(256, 2) void dense_block_k(
    const unsigned short* __restrict__ hin,   // [9216][64] bf16
    const unsigned short* __restrict__ wb,    // this db's 129024-hw segment
    const float* __restrict__ b1, const float* __restrict__ b2,
    const float* __restrict__ b3, const float* __restrict__ b4,
    const float* __restrict__ b5,
    float alpha, const float* __restrict__ r1, float beta,
    const float* __restrict__ r2, float gamma,
    unsigned short* __restrict__ hout,        // [9216][64] bf16 (next h)
    float* out_fp)                            // fp32 NHWC [9216][64]
{
    const int tile = blockIdx.x;              // 0..575
    const int tx0 = (tile % 24) * 4, ty0 = (tile / 24) * 4;
    const int tid = threadIdx.x;
    const int wid = tid >> 6, lane = tid & 63;
    const int l16 = lane & 15, q = lane >> 4;

    __shared__ unsigned short s[196 * CSTR];  // 53312 B -> 2 blocks/CU

    // stage h into ch 0..63 (rows ty0-5..ty0+8, cols tx0-5..tx0+8); zero 64..127
    for (int i = tid; i < 196 * 16; i += 256) {
        int p = i >> 4, g = i & 15;
        int ly = p / 14, lx = p - ly * 14;
        int gy = ty0 - 5 + ly, gx = tx0 - 5 + lx;
        uint4 v = {0u, 0u, 0u, 0u};
        if (g < 8 && gy >= 0 && gy < 96 && gx >= 0 && gx < 96)
            v = *(const uint4*)&hin[(size_t)(gy * 96 + gx) * 64 + g * 8];
        *(uint4*)&s[p * CSTR + g * 8] = v;
    }
    __syncthreads();

    growth_stage<12, 1,  64,  64, false>(s, wb,         b1, wid, l16, q); __syncthreads();
    growth_stage<10, 2,  96,  80, false>(s, wb + 9216,  b2, wid, l16, q); __syncthreads();
    growth_stage< 8, 3,  96,  96, true >(s, wb + 23040, b3, wid, l16, q); __syncthreads();
    growth_stage< 6, 4, 128, 112, true >(s, wb + 36864, b4, wid, l16, q); __syncthreads();

    // cv5: OC=64, out 4x4; wave = mt (16 oc), one px-tile, 2 K-half chains.
    // Output (ty0+row, tx0+col) window top-left = region (4+row, 4+col).
    {
        const unsigned short* wst = wb + 55296;
        const int row = l16 >> 2, col = l16 & 3;
        const int lp0 = (4 + row) * RSTR + (4 + col);
        f32x4 a0 = {0.f,0.f,0.f,0.f}, a1 = {0.f,0.f,0.f,0.f};
        #pragma unroll
        for (int kb = 0; kb < 64; kb += 32) {
            #pragma unroll
            for (int tap = 0; tap < 9; ++tap) {
                const int dy = tap / 3, dx = tap - dy * 3;
                bf16x8 a = *(const bf16x8*)&wst[(tap * 64 + wid * 16 + l16) * 128 + kb + q * 8];
                bf16x8 b = *(const bf16x8*)&s[(lp0 + dy * RSTR + dx) * CSTR + kb + q * 8];
                a0 = __builtin_amdgcn_mfma_f32_16x16x32_bf16(a, b, a0, 0, 0, 0);
            }
        }
        #pragma unroll
        for (int kb = 64; kb < 128; kb += 32) {
            #pragma unroll
            for (int tap = 0; tap < 9; ++tap) {
                const int dy = tap / 3, dx = tap - dy * 3;
                bf16x8 a = *(const bf16x8*)&wst[(tap * 64 + wid * 16 + l16) * 128 + kb + q * 8];
                bf16x8 b = *(const bf16x8*)&s[(lp0 + dy * RSTR + dx) * CSTR + kb + q * 8];
                a1 = __builtin_amdgcn_mfma_f32_16x16x32_bf16(a, b, a1, 0, 0, 0);
            }
        }
        f32x4 acc = a0 + a1;
        const float4 bv = *(const float4*)&b5[wid * 16 + q * 4];
        const int ocb = wid * 16 + q * 4;
        size_t pix = (size_t)((ty0 + row) * 96 + tx0 + col);
        float4 res1, res2;
        if (r1) res1 = *(const float4*)&r1[pix * 64 + ocb];
        if (r2) res2 = *(const float4*)&r2[pix * 64 + ocb];
        float vv[4];
        #pragma unroll
        for (int r = 0; r < 4; ++r) {
            float v = acc[r] + ((const float*)&bv)[r];
            v *= alpha;
            if (r1) v += beta  * ((const float*)&res1)[r];
            if (r2) v += gamma * ((const float*)&res2)[r];
            vv[r] = v;
        }
        ushort4 o = {f2bf(vv[0]), f2bf(vv[1]), f2bf(vv[2]), f2bf(vv[3])};
        *(ushort4*)&hout[pix * 64 + ocb] = o;
        float4 of = {vv[0], vv[1], vv[2], vv[3]};
        *(float4*)&out_fp[pix * 64 + ocb] = of;
    }
}

// ---------------------------------------------------------------------------
// MFMA 3x3 conv for c2 (64->64), 8x4 px tile, 288 blocks.
// ---------------------------------------------------------------------------
__global__ __launch_bounds__(256) void conv_mfma_k(
    const unsigned short* __restrict__ act, int cstride, int IC, int ICp,
    const unsigned short* __restrict__ wb,
    const float* __restrict__ bias,
    float alpha, const float* __restrict__ r1, float beta,
    float* __restrict__ out_fp)
{
    const int tile = blockIdx.x;             // 0..287
    const int tx0 = (tile % 12) * 8, ty0 = (tile / 12) * 4;
    const int tid = threadIdx.x;
    const int wid = tid >> 6, lane = tid & 63;
    const int l16 = lane & 15, q = lane >> 4;
    const int stride = ICp + 8;

    __shared__ unsigned short s[60 * 136];

    const int NG = ICp >> 3;
    for (int i = tid; i < 60 * NG; i += 256) {
        int hp = i / NG, g = i - hp * NG;
        int row = hp / 10, col = hp - row * 10;
        int gy = ty0 - 1 + row, gx = tx0 - 1 + col;
        int gc = g * 8;
        uint4 v = {0u, 0u, 0u, 0u};
        if (gy >= 0 && gy < 96 && gx >= 0 && gx < 96 && gc < IC)
            v = *reinterpret_cast<const uint4*>(
                    &act[(size_t)(gy * 96 + gx) * cstride + gc]);
        *reinterpret_cast<uint4*>(&s[hp * stride + gc]) = v;
    }
    __syncthreads();

    const int mt = wid;
    f32x4 acc0 = {0.f, 0.f, 0.f, 0.f}, acc1 = {0.f, 0.f, 0.f, 0.f};
    const int arow = (mt * 16 + l16) * ICp + q * 8;
    const int yy0 = l16 >> 3, xx0 = l16 & 7;
    const int yy1 = 2 + (l16 >> 3), xx1 = l16 & 7;
    for (int icb = 0; icb < ICp; icb += 32) {
        #pragma unroll
        for (int tap = 0; tap < 9; ++tap) {
            const int dy = tap / 3, dx = tap - dy * 3;
            bf16x8 a = *(const bf16x8*)&wb[(size_t)tap * 64 * ICp + arow + icb];
            bf16x8 b0 = *(const bf16x8*)&s[((yy0 + dy) * 10 + xx0 + dx) * stride + icb + q * 8];
            acc0 = __builtin_amdgcn_mfma_f32_16x16x32_bf16(a, b0, acc0, 0, 0, 0);
            bf16x8 b1 = *(const bf16x8*)&s[((yy1 + dy) * 10 + xx1 + dx) * stride + icb + q * 8];
            acc1 = __builtin_amdgcn_mfma_f32_16x16x32_bf16(a, b1, acc1, 0, 0, 0);
        }
    }
    const float4 bv = *(const float4*)&bias[mt * 16 + q * 4];
    #pragma unroll
    for (int nt = 0; nt < 2; ++nt) {
        f32x4 acc = nt ? acc1 : acc0;
        int p = nt * 16 + l16;
        size_t pix = (size_t)((ty0 + (p >> 3)) * 96 + tx0 + (p & 7));
        int ocb = mt * 16 + q * 4;
        float4 res1;
        if (r1) res1 = *(const float4*)&r1[pix * 64 + ocb];
        float4 o;
        #pragma unroll
        for (int r = 0; r < 4; ++r) {
            float v = acc[r] + ((const float*)&bv)[r];
            v *= alpha;
            if (r1) v += beta * ((const float*)&res1)[r];
            ((float*)&o)[r] = v;
        }
        *(float4*)&out_fp[pix * 64 + ocb] = o;
    }
}

// ---------------------------------------------------------------------------
// MLP: WtT[f][t] = fc2_b[f] + sum_j lrelu(a[j]*t + c[j]) * fc2_w[j][f]
// ---------------------------------------------------------------------------
__global__ __launch_bounds__(256) void mlp_k(
    const float* __restrict__ fc1_w, const float* __restrict__ fc1_b,
    const float* __restrict__ fc2_w, const float* __restrict__ fc2_b,
    float* __restrict__ WtT)
{
    const int f0 = blockIdx.x * 64, t0 = blockIdx.y * 64;
    const int tid = threadIdx.x;
    const int ft = tid & 15, tt = tid >> 4;
    __shared__ float sa[256], sc[256];
    __shared__ float swt[64][64];
    sa[tid] = fc1_w[tid] + fc1_w[256 + tid];
    sc[tid] = 2.f * fc1_w[512 + tid] + fc1_b[tid];
    float acc[4][4] = {};
    const float tbase = (float)(t0 + tt * 4);
    for (int jc = 0; jc < 256; jc += 64) {
        __syncthreads();
        for (int i = tid; i < 4096; i += 256) {
            int j = i >> 6, f = i & 63;
            swt[j][f] = fc2_w[(size_t)(jc + j) * 1728 + f0 + f];
        }
        __syncthreads();
        for (int j = 0; j < 64; ++j) {
            float4 wv = *(const float4*)&swt[j][ft * 4];
            float aj = sa[jc + j], cj = sc[jc + j];
            #pragma unroll
            for (int v = 0; v < 4; ++v) {
                float h = aj * (tbase + (float)v) + cj;
                h = (h > 0.f) ? h : 0.2f * h;
                acc[0][v] += h * wv.x;
                acc[1][v] += h * wv.y;
                acc[2][v] += h * wv.z;
                acc[3][v] += h * wv.w;
            }
        }
    }
    #pragma unroll
    for (int u = 0; u < 4; ++u) {
        int f = f0 + ft * 4 + u;
        float b = fc2_b[f];
        float4 o = {acc[u][0] + b, acc[u][1] + b, acc[u][2] + b, acc[u][3] + b};
        *(float4*)&WtT[(size_t)f * 192 + t0 + tt * 4] = o;
    }
}

// ---------------------------------------------------------------------------
// Final dynamic-filter gather; feat is fp32 NHWC [9216][64]
// ---------------------------------------------------------------------------
__global__ __launch_bounds__(256) void dynfilter_k(
    const float* __restrict__ feat,
    const float* __restrict__ WtT,
    float* __restrict__ out)
{
    const int h   = blockIdx.y;
    const int w0  = blockIdx.x * 64;
    const int tid = threadIdx.x;
    const int lw  = tid & 63, kc = tid >> 6;
    const int ybase = h / 2 - 1;
    const int x0lo  = w0 / 2 - 1;

    __shared__ float s_f[64][3][36];
    __shared__ float s_red[4][64];

    for (int i = tid; i < 64 * 102; i += 256) {
        int k = i & 63, j = i >> 6;
        int di = j / 34, col = j - di * 34;
        int yv = ybase + di, xv = x0lo + col;
        float v = 0.f;
        if (yv >= 0 && yv < Hh && xv >= 0 && xv < Ww)
            v = feat[(size_t)(yv * Ww + xv) * 64 + k];
        s_f[k][di][col] = v;
    }
    __syncthreads();

    const int w = w0 + lw;
    const int qq = w % 3;
    const int t = (h % 3) * 64 + w / 3;
    const int lx = (w / 2 - 1) - x0lo;
    const float* Wp = WtT + (size_t)(qq * 576 + kc * 144) * 192 + t;
    float acc = 0.f;
    for (int k = 0; k < 16; ++k) {
        #pragma unroll
        for (int di = 0; di < 3; ++di)
            #pragma unroll
            for (int dj = 0; dj < 3; ++dj)
                acc += s_f[kc * 16 + k][di][lx + dj]
                     * Wp[(size_t)(k * 9 + di * 3 + dj) * 192];
    }
    s_red[kc][lw] = acc;
    __syncthreads();
    if (kc == 0) {
        float v = s_red[0][lw] + s_red[1][lw] + s_red[2][lw] + s_red[3][lw];
        int o = h * 192 + w;
        out[o] = v;
        out[36864 + o] = v;
        out[2 * 36864 + o] = v;
    }
}

// ---------------------------------------------------------------------------
extern "C" void kernel_launch(void* const* d_in, const int* in_sizes, int n_in,
                              void* d_out, int out_size, void* d_ws, size_t ws_size,
                              hipStream_t stream)
{
    const float* x     = (const float*)d_in[0];
    const float* c1_w  = (const float*)d_in[1];
    const float* c1_b  = (const float*)d_in[2];
    const float* dbw[5] = {(const float*)d_in[3], (const float*)d_in[5],
                           (const float*)d_in[7], (const float*)d_in[9],
                           (const float*)d_in[11]};
    const float* dbb[5] = {(const float*)d_in[4], (const float*)d_in[6],
                           (const float*)d_in[8], (const float*)d_in[10],
                           (const float*)d_in[12]};
    const float* c2_w  = (const float*)d_in[13];
    const float* c2_b  = (const float*)d_in[14];
    const float* fc1_w = (const float*)d_in[15];
    const float* fc1_b = (const float*)d_in[16];
    const float* fc2_w = (const float*)d_in[17];
    const float* fc2_b = (const float*)d_in[18];

    float* ws    = (float*)d_ws;
    float* x0f   = ws;                    // [9216][64] fp32
    float* hfA   = ws + (size_t)NPIX;
    float* hfB   = ws + 2 * (size_t)NPIX;
    float* featf = ws + 3 * (size_t)NPIX;
    unsigned short* dbaA = (unsigned short*)(ws + 4 * (size_t)NPIX); // [9216][64] bf16
    unsigned short* dbaB = dbaA + (size_t)9216 * 64;
    unsigned short* wb   = dbaB + (size_t)9216 * 64;                 // 1585152 hw
    float* WtT = (float*)(wb + (size_t)1585152 + 128);               // 1728*192 f32
    float* ff  = hfA;

    prep_w_k<<<6192, 256, 0, stream>>>(dbw[0], dbw[1], dbw[2], dbw[3], dbw[4],
                                       c2_w, wb);
    c1_k<<<36, 256, 0, stream>>>(x, c1_w, c1_b, x0f, dbaA);

    for (int d = 0; d < 12; ++d) {
        unsigned short* hin  = (d & 1) ? dbaB : dbaA;
        unsigned short* hout = (d & 1) ? dbaA : dbaB;
        const float* featprev = (d < 3) ? x0f : featf;
        const unsigned short* wseg = wb + (size_t)d * 129024;
        const float* b1 = dbb[0] + (size_t)d * 16;
        const float* b2 = dbb[1] + (size_t)d * 16;
        const float* b3 = dbb[2] + (size_t)d * 16;
        const float* b4 = dbb[3] + (size_t)d * 16;
        const float* b5 = dbb[4] + (size_t)d * 64;
        int pos = d % 3;
        if (pos == 0)
            dense_block_k<<<576, 256, 0, stream>>>(hin, wseg, b1, b2, b3, b4, b5,
                0.2f, featprev, 1.f, nullptr, 0.f, hout, hfA);
        else if (pos == 1)
            dense_block_k<<<576, 256, 0, stream>>>(hin, wseg, b1, b2, b3, b4, b5,
                0.2f, hfA, 1.f, nullptr, 0.f, hout, hfB);
        else
            dense_block_k<<<576, 256, 0, stream>>>(hin, wseg, b1, b2, b3, b4, b5,
                0.04f, hfB, 0.2f, featprev, 1.f, hout, featf);
    }

    // c2: ff = conv(dbaA) + x0
    conv_mfma_k<<<288, 256, 0, stream>>>(dbaA, 64, 64, 64,
        wb + (size_t)12 * 129024, c2_b, 1.f, x0f, 1.f, ff);

    mlp_k<<<dim3(27, 3), 256, 0, stream>>>(fc1_w, fc1_b, fc2_w, fc2_b, WtT);
    dynfilter_k<<<dim3(3, 192), 256, 0, stream>>>(ff, WtT, (float*)d_out);
}

// Round 13
// 519.821 us; speedup vs baseline: 1.2373x; 1.2373x over previous
//
#include <hip/hip_runtime.h>

#define Hh 96
#define Ww 96
#define HW 9216
#define NPIX 589824   // 9216*64

typedef __attribute__((ext_vector_type(8))) short bf16x8;
typedef __attribute__((ext_vector_type(4))) float f32x4;

__device__ __forceinline__ unsigned short f2bf(float f) {
    unsigned int u = __float_as_uint(f);
    u += 0x7fff + ((u >> 16) & 1);          // RNE
    return (unsigned short)(u >> 16);
}

// ---------------------------------------------------------------------------
// Weight prep: fp32 OIHW -> bf16 [tap][oc][ICp] per conv, ICp zero-padded.
// ---------------------------------------------------------------------------
__global__ __launch_bounds__(256) void prep_w_k(
    const float* __restrict__ w0, const float* __restrict__ w1,
    const float* __restrict__ w2, const float* __restrict__ w3,
    const float* __restrict__ w4, const float* __restrict__ c2w,
    unsigned short* __restrict__ wb)
{
    int idx = blockIdx.x * 256 + threadIdx.x;
    const int DBSZ = 129024, TOT_DB = 12 * 129024;
    if (idx >= TOT_DB + 36864) return;
    float val;
    if (idx < TOT_DB) {
        int d = idx / DBSZ, rem = idx - d * DBSZ;
        int base, OC, IC, ICp; const float* wp;
        if      (rem < 9216)  { base = 0;     OC = 16; IC = 64;  ICp = 64;  wp = w0; }
        else if (rem < 23040) { base = 9216;  OC = 16; IC = 80;  ICp = 96;  wp = w1; }
        else if (rem < 36864) { base = 23040; OC = 16; IC = 96;  ICp = 96;  wp = w2; }
        else if (rem < 55296) { base = 36864; OC = 16; IC = 112; ICp = 128; wp = w3; }
        else                  { base = 55296; OC = 64; IC = 128; ICp = 128; wp = w4; }
        int e   = rem - base;
        int tap = e / (OC * ICp);
        int r   = e - tap * (OC * ICp);
        int oc  = r / ICp, icp = r - oc * ICp;
        val = (icp < IC) ? wp[(((size_t)d * OC + oc) * IC + icp) * 9 + tap] : 0.f;
    } else {
        int e = idx - TOT_DB;
        int tap = e / 4096, r = e & 4095;
        int oc = r >> 6, icp = r & 63;
        val = c2w[((size_t)(oc * 64 + icp)) * 9 + tap];
    }
    wb[idx] = f2bf(val);
}

// ---------------------------------------------------------------------------
// c1: 3->64 conv from NCHW fp32 x; writes x0f (fp32 NHWC) + dba (bf16 [9216][64])
// ---------------------------------------------------------------------------
__global__ __launch_bounds__(256) void c1_k(
    const float* __restrict__ x, const float* __restrict__ w,
    const float* __restrict__ bias,
    float* __restrict__ x0f, unsigned short* __restrict__ dba)
{
    __shared__ float sw[1728];
    __shared__ float sb[64];
    int tid = threadIdx.x;
    for (int i = tid; i < 1728; i += 256) sw[i] = w[i];
    if (tid < 64) sb[tid] = bias[tid];
    __syncthreads();
    int px = blockIdx.x * 256 + tid;
    int gy = px / 96, gx = px - (px / 96) * 96;
    float in[3][3][3];
    #pragma unroll
    for (int c = 0; c < 3; ++c)
        #pragma unroll
        for (int dy = 0; dy < 3; ++dy)
            #pragma unroll
            for (int dx = 0; dx < 3; ++dx) {
                int yy = gy - 1 + dy, xx = gx - 1 + dx;
                in[c][dy][dx] = (yy >= 0 && yy < 96 && xx >= 0 && xx < 96)
                                ? x[c * HW + yy * 96 + xx] : 0.f;
            }
    for (int oc = 0; oc < 64; ++oc) {
        float acc = sb[oc];
        const float* wp = &sw[oc * 27];
        #pragma unroll
        for (int c = 0; c < 3; ++c)
            #pragma unroll
            for (int dy = 0; dy < 3; ++dy)
                #pragma unroll
                for (int dx = 0; dx < 3; ++dx)
                    acc += wp[(c * 3 + dy) * 3 + dx] * in[c][dy][dx];
        x0f[(size_t)px * 64 + oc] = acc;
        dba[(size_t)px * 64 + oc] = f2bf(acc);
    }
}

// ---------------------------------------------------------------------------
// Fused dense block (R7 geometry: 256 thr / 4 waves, 8x4 out tile, 14x18
// halo, clamp-and-discard, 68.5 KB LDS, grid 288).
// R13 change: EXPLICIT 2-DEEP SOFTWARE PIPELINE. Evidence: R7's measured
// ~346 cyc per (a-read + b-read + MFMA) group == the sum of raw latencies
// (L2 ~200 + LDS ~120 + dep ~30) -> compiler does NOT hoist loads across
// these unrolled bodies. Fix: flatten (kb,tap) into one iteration space,
// rotate 3 named register slots, issue loads for it+2 in program order
// before the MFMAs of it. All slot indices compile-time after unroll.
// ---------------------------------------------------------------------------
#define CSTR 136
#define RSTR 18   // region row stride in px

template<int NR, int NC, int BS, int ICP, int OCH>
__device__ __forceinline__ void growth_stage(
    unsigned short* s, const unsigned short* __restrict__ wst,
    const float* __restrict__ bias, int wid, int l16, int q)
{
    constexpr int NPXr = NR * NC;
    constexpr int NT = (NPXr + 15) / 16;
    constexpr int MX = (NT + 3) / 4;
    constexpr int NIT = (ICP / 32) * 9;
    f32x4 acc[MX];
    int lp0[MX], outp[MX];
    bool ok[MX];
    #pragma unroll
    for (int i = 0; i < MX; ++i) {
        int nt = wid + i * 4;
        int p  = nt * 16 + l16;
        bool live = (nt < NT) && (p < NPXr);
        ok[i] = live;
        int pc = live ? p : 0;            // clamp: reads stay in-bounds
        int r = pc / NC, c = pc - (pc / NC) * NC;
        lp0[i]  = (BS - 1 + r) * RSTR + (BS - 1 + c);
        outp[i] = (BS + r) * RSTR + (BS + c);
        acc[i]  = (f32x4){0.f, 0.f, 0.f, 0.f};
    }
    bf16x8 av[3];
    bf16x8 bv[3][MX];
    auto gs_load = [&](int J) {
        int kb = (J / 9) * 32, tap = J - (J / 9) * 9;
        int dy = tap / 3, dx = tap - dy * 3;
        av[J % 3] = *(const bf16x8*)&wst[(tap * 16 + l16) * ICP + kb + q * 8];
        #pragma unroll
        for (int i = 0; i < MX; ++i)
            bv[J % 3][i] = *(const bf16x8*)&s[(lp0[i] + dy * RSTR + dx) * CSTR + kb + q * 8];
    };
    gs_load(0);
    gs_load(1);
    #pragma unroll
    for (int it = 0; it < NIT; ++it) {
        if (it + 2 < NIT) gs_load(it + 2);   // compile-time condition after unroll
        bf16x8 a = av[it % 3];
        #pragma unroll
        for (int i = 0; i < MX; ++i)
            acc[i] = __builtin_amdgcn_mfma_f32_16x16x32_bf16(a, bv[it % 3][i], acc[i], 0, 0, 0);
    }
    const float4 bvb = *(const float4*)&bias[q * 4];
    #pragma unroll
    for (int i = 0; i < MX; ++i) {
        if (!ok[i]) continue;
        float v0 = acc[i][0] + bvb.x; v0 = v0 > 0.f ? v0 : 0.2f * v0;
        float v1 = acc[i][1] + bvb.y; v1 = v1 > 0.f ? v1 : 0.2f * v1;
        float v2 = acc[i][2] + bvb.z; v2 = v2 > 0.f ? v2 : 0.2f * v2;
        float v3 = acc[i][3] + bvb.w; v3 = v3 > 0.f ? v3 : 0.2f * v3;
        ushort4 o = {f2bf(v0), f2bf(v1), f2bf(v2), f2bf(v3)};
        *(ushort4*)&s[outp[i] * CSTR + OCH + q * 4] = o;
    }
}

__global__ __launch_bounds__(256) void dense_block_k(
    const unsigned short* __restrict__ hin,   // [9216][64] bf16
    const unsigned short* __restrict__ wb,    // this db's 129024-hw segment
    const float* __restrict__ b1, const float* __restrict__ b2,
    const float* __restrict__ b3, const float* __restrict__ b4,
    const float* __restrict__ b5,
    float alpha, const float* __restrict__ r1, float beta,
    const float* __restrict__ r2, float gamma,
    unsigned short* __restrict__ hout,        // [9216][64] bf16 (next h)
    float* out_fp)                            // fp32 NHWC [9216][64]
{
    const int tile = blockIdx.x;              // 0..287
    const int tx0 = (tile % 12) * 8, ty0 = (tile / 12) * 4;
    const int tid = threadIdx.x;
    const int wid = tid >> 6, lane = tid & 63;
    const int l16 = lane & 15, q = lane >> 4;

    __shared__ unsigned short s[252 * CSTR];  // 68544 B

    // stage h into ch 0..63 (rows ty0-5..ty0+8, cols tx0-5..tx0+12); zero 64..127
    for (int i = tid; i < 252 * 16; i += 256) {
        int p = i >> 4, g = i & 15;
        int ly = p / 18, lx = p - ly * 18;
        int gy = ty0 - 5 + ly, gx = tx0 - 5 + lx;
        uint4 v = {0u, 0u, 0u, 0u};
        if (g < 8 && gy >= 0 && gy < 96 && gx >= 0 && gx < 96)
            v = *(const uint4*)&hin[(size_t)(gy * 96 + gx) * 64 + g * 8];
        *(uint4*)&s[p * CSTR + g * 8] = v;
    }
    __syncthreads();

    growth_stage<12, 16, 1,  64,  64>(s, wb,         b1, wid, l16, q); __syncthreads();
    growth_stage<10, 14, 2,  96,  80>(s, wb + 9216,  b2, wid, l16, q); __syncthreads();
    growth_stage< 8, 12, 3,  96,  96>(s, wb + 23040, b3, wid, l16, q); __syncthreads();
    growth_stage< 6, 10, 4, 128, 112>(s, wb + 36864, b4, wid, l16, q); __syncthreads();

    // cv5: OC=64, out 4 rows x 8 cols; wave = mt (16 oc), 2 px-tiles,
    // same 2-deep pipelined slot rotation. Window top-left = (4+row, 4+col).
    {
        const unsigned short* wst = wb + 55296;
        int lp0c[2];
        #pragma unroll
        for (int nt = 0; nt < 2; ++nt) {
            int p = nt * 16 + l16;
            lp0c[nt] = (4 + (p >> 3)) * RSTR + (4 + (p & 7));
        }
        f32x4 acc5[2];
        acc5[0] = (f32x4){0.f, 0.f, 0.f, 0.f};
        acc5[1] = (f32x4){0.f, 0.f, 0.f, 0.f};
        bf16x8 av[3];
        bf16x8 bv[3][2];
        auto c5_load = [&](int J) {
            int kb = (J / 9) * 32, tap = J - (J / 9) * 9;
            int dy = tap / 3, dx = tap - dy * 3;
            av[J % 3] = *(const bf16x8*)&wst[(tap * 64 + wid * 16 + l16) * 128 + kb + q * 8];
            #pragma unroll
            for (int i = 0; i < 2; ++i)
                bv[J % 3][i] = *(const bf16x8*)&s[(lp0c[i] + dy * RSTR + dx) * CSTR + kb + q * 8];
        };
        c5_load(0);
        c5_load(1);
        #pragma unroll
        for (int it = 0; it < 36; ++it) {
            if (it + 2 < 36) c5_load(it + 2);
            bf16x8 a = av[it % 3];
            #pragma unroll
            for (int i = 0; i < 2; ++i)
                acc5[i] = __builtin_amdgcn_mfma_f32_16x16x32_bf16(a, bv[it % 3][i], acc5[i], 0, 0, 0);
        }
        const float4 bvb = *(const float4*)&b5[wid * 16 + q * 4];
        const int ocb = wid * 16 + q * 4;
        #pragma unroll
        for (int nt = 0; nt < 2; ++nt) {
            int p = nt * 16 + l16;
            int row = p >> 3, col = p & 7;
            size_t pix = (size_t)((ty0 + row) * 96 + tx0 + col);
            float4 res1, res2;
            if (r1) res1 = *(const float4*)&r1[pix * 64 + ocb];
            if (r2) res2 = *(const float4*)&r2[pix * 64 + ocb];
            float vv[4];
            #pragma unroll
            for (int r = 0; r < 4; ++r) {
                float v = acc5[nt][r] + ((const float*)&bvb)[r];
                v *= alpha;
                if (r1) v += beta  * ((const float*)&res1)[r];
                if (r2) v += gamma * ((const float*)&res2)[r];
                vv[r] = v;
            }
            ushort4 o = {f2bf(vv[0]), f2bf(vv[1]), f2bf(vv[2]), f2bf(vv[3])};
            *(ushort4*)&hout[pix * 64 + ocb] = o;
            float4 of = {vv[0], vv[1], vv[2], vv[3]};
            *(float4*)&out_fp[pix * 64 + ocb] = of;
        }
    }
}

// ---------------------------------------------------------------------------
// MFMA 3x3 conv for c2 (64->64), 8x4 px tile, 288 blocks.
// ---------------------------------------------------------------------------
__global__ __launch_bounds__(256) void conv_mfma_k(
    const unsigned short* __restrict__ act, int cstride, int IC, int ICp,
    const unsigned short* __restrict__ wb,
    const float* __restrict__ bias,
    float alpha, const float* __restrict__ r1, float beta,
    float* __restrict__ out_fp)
{
    const int tile = blockIdx.x;             // 0..287
    const int tx0 = (tile % 12) * 8, ty0 = (tile / 12) * 4;
    const int tid = threadIdx.x;
    const int wid = tid >> 6, lane = tid & 63;
    const int l16 = lane & 15, q = lane >> 4;
    const int stride = ICp + 8;

    __shared__ unsigned short s[60 * 136];

    const int NG = ICp >> 3;
    for (int i = tid; i < 60 * NG; i += 256) {
        int hp = i / NG, g = i - hp * NG;
        int row = hp / 10, col = hp - row * 10;
        int gy = ty0 - 1 + row, gx = tx0 - 1 + col;
        int gc = g * 8;
        uint4 v = {0u, 0u, 0u, 0u};
        if (gy >= 0 && gy < 96 && gx >= 0 && gx < 96 && gc < IC)
            v = *reinterpret_cast<const uint4*>(
                    &act[(size_t)(gy * 96 + gx) * cstride + gc]);
        *reinterpret_cast<uint4*>(&s[hp * stride + gc]) = v;
    }
    __syncthreads();

    const int mt = wid;
    f32x4 acc0 = {0.f, 0.f, 0.f, 0.f}, acc1 = {0.f, 0.f, 0.f, 0.f};
    const int arow = (mt * 16 + l16) * ICp + q * 8;
    const int yy0 = l16 >> 3, xx0 = l16 & 7;
    const int yy1 = 2 + (l16 >> 3), xx1 = l16 & 7;
    for (int icb = 0; icb < ICp; icb += 32) {
        #pragma unroll
        for (int tap = 0; tap < 9; ++tap) {
            const int dy = tap / 3, dx = tap - dy * 3;
            bf16x8 a = *(const bf16x8*)&wb[(size_t)tap * 64 * ICp + arow + icb];
            bf16x8 b0 = *(const bf16x8*)&s[((yy0 + dy) * 10 + xx0 + dx) * stride + icb + q * 8];
            acc0 = __builtin_amdgcn_mfma_f32_16x16x32_bf16(a, b0, acc0, 0, 0, 0);
            bf16x8 b1 = *(const bf16x8*)&s[((yy1 + dy) * 10 + xx1 + dx) * stride + icb + q * 8];
            acc1 = __builtin_amdgcn_mfma_f32_16x16x32_bf16(a, b1, acc1, 0, 0, 0);
        }
    }
    const float4 bv = *(const float4*)&bias[mt * 16 + q * 4];
    #pragma unroll
    for (int nt = 0; nt < 2; ++nt) {
        f32x4 acc = nt ? acc1 : acc0;
        int p = nt * 16 + l16;
        size_t pix = (size_t)((ty0 + (p >> 3)) * 96 + tx0 + (p & 7));
        int ocb = mt * 16 + q * 4;
        float4 res1;
        if (r1) res1 = *(const float4*)&r1[pix * 64 + ocb];
        float4 o;
        #pragma unroll
        for (int r = 0; r < 4; ++r) {
            float v = acc[r] + ((const float*)&bv)[r];
            v *= alpha;
            if (r1) v += beta * ((const float*)&res1)[r];
            ((float*)&o)[r] = v;
        }
        *(float4*)&out_fp[pix * 64 + ocb] = o;
    }
}

// ---------------------------------------------------------------------------
// MLP: WtT[f][t] = fc2_b[f] + sum_j lrelu(a[j]*t + c[j]) * fc2_w[j][f]
// ---------------------------------------------------------------------------
__global__ __launch_bounds__(256) void mlp_k(
    const float* __restrict__ fc1_w, const float* __restrict__ fc1_b,
    const float* __restrict__ fc2_w, const float* __restrict__ fc2_b,
    float* __restrict__ WtT)
{
    const int f0 = blockIdx.x * 64, t0 = blockIdx.y * 64;
    const int tid = threadIdx.x;
    const int ft = tid & 15, tt = tid >> 4;
    __shared__ float sa[256], sc[256];
    __shared__ float swt[64][64];
    sa[tid] = fc1_w[tid] + fc1_w[256 + tid];
    sc[tid] = 2.f * fc1_w[512 + tid] + fc1_b[tid];
    float acc[4][4] = {};
    const float tbase = (float)(t0 + tt * 4);
    for (int jc = 0; jc < 256; jc += 64) {
        __syncthreads();
        for (int i = tid; i < 4096; i += 256) {
            int j = i >> 6, f = i & 63;
            swt[j][f] = fc2_w[(size_t)(jc + j) * 1728 + f0 + f];
        }
        __syncthreads();
        for (int j = 0; j < 64; ++j) {
            float4 wv = *(const float4*)&swt[j][ft * 4];
            float aj = sa[jc + j], cj = sc[jc + j];
            #pragma unroll
            for (int v = 0; v < 4; ++v) {
                float h = aj * (tbase + (float)v) + cj;
                h = (h > 0.f) ? h : 0.2f * h;
                acc[0][v] += h * wv.x;
                acc[1][v] += h * wv.y;
                acc[2][v] += h * wv.z;
                acc[3][v] += h * wv.w;
            }
        }
    }
    #pragma unroll
    for (int u = 0; u < 4; ++u) {
        int f = f0 + ft * 4 + u;
        float b = fc2_b[f];
        float4 o = {acc[u][0] + b, acc[u][1] + b, acc[u][2] + b, acc[u][3] + b};
        *(float4*)&WtT[(size_t)f * 192 + t0 + tt * 4] = o;
    }
}

// ---------------------------------------------------------------------------
// Final dynamic-filter gather; feat is fp32 NHWC [9216][64]
// ---------------------------------------------------------------------------
__global__ __launch_bounds__(256) void dynfilter_k(
    const float* __restrict__ feat,
    const float* __restrict__ WtT,
    float* __restrict__ out)
{
    const int h   = blockIdx.y;
    const int w0  = blockIdx.x * 64;
    const int tid = threadIdx.x;
    const int lw  = tid & 63, kc = tid >> 6;
    const int ybase = h / 2 - 1;
    const int x0lo  = w0 / 2 - 1;

    __shared__ float s_f[64][3][36];
    __shared__ float s_red[4][64];

    for (int i = tid; i < 64 * 102; i += 256) {
        int k = i & 63, j = i >> 6;
        int di = j / 34, col = j - di * 34;
        int yv = ybase + di, xv = x0lo + col;
        float v = 0.f;
        if (yv >= 0 && yv < Hh && xv >= 0 && xv < Ww)
            v = feat[(size_t)(yv * Ww + xv) * 64 + k];
        s_f[k][di][col] = v;
    }
    __syncthreads();

    const int w = w0 + lw;
    const int qq = w % 3;
    const int t = (h % 3) * 64 + w / 3;
    const int lx = (w / 2 - 1) - x0lo;
    const float* Wp = WtT + (size_t)(qq * 576 + kc * 144) * 192 + t;
    float acc = 0.f;
    for (int k = 0; k < 16; ++k) {
        #pragma unroll
        for (int di = 0; di < 3; ++di)
            #pragma unroll
            for (int dj = 0; dj < 3; ++dj)
                acc += s_f[kc * 16 + k][di][lx + dj]
                     * Wp[(size_t)(k * 9 + di * 3 + dj) * 192];
    }
    s_red[kc][lw] = acc;
    __syncthreads();
    if (kc == 0) {
        float v = s_red[0][lw] + s_red[1][lw] + s_red[2][lw] + s_red[3][lw];
        int o = h * 192 + w;
        out[o] = v;
        out[36864 + o] = v;
        out[2 * 36864 + o] = v;
    }
}

// ---------------------------------------------------------------------------
extern "C" void kernel_launch(void* const* d_in, const int* in_sizes, int n_in,
                              void* d_out, int out_size, void* d_ws, size_t ws_size,
                              hipStream_t stream)
{
    const float* x     = (const float*)d_in[0];
    const float* c1_w  = (const float*)d_in[1];
    const float* c1_b  = (const float*)d_in[2];
    const float* dbw[5] = {(const float*)d_in[3], (const float*)d_in[5],
                           (const float*)d_in[7], (const float*)d_in[9],
                           (const float*)d_in[11]};
    const float* dbb[5] = {(const float*)d_in[4], (const float*)d_in[6],
                           (const float*)d_in[8], (const float*)d_in[10],
                           (const float*)d_in[12]};
    const float* c2_w  = (const float*)d_in[13];
    const float* c2_b  = (const float*)d_in[14];
    const float* fc1_w = (const float*)d_in[15];
    const float* fc1_b = (const float*)d_in[16];
    const float* fc2_w = (const float*)d_in[17];
    const float* fc2_b = (const float*)d_in[18];

    float* ws    = (float*)d_ws;
    float* x0f   = ws;                    // [9216][64] fp32
    float* hfA   = ws + (size_t)NPIX;
    float* hfB   = ws + 2 * (size_t)NPIX;
    float* featf = ws + 3 * (size_t)NPIX;
    unsigned short* dbaA = (unsigned short*)(ws + 4 * (size_t)NPIX); // [9216][64] bf16
    unsigned short* dbaB = dbaA + (size_t)9216 * 64;
    unsigned short* wb   = dbaB + (size_t)9216 * 64;                 // 1585152 hw
    float* WtT = (float*)(wb + (size_t)1585152 + 128);               // 1728*192 f32
    float* ff  = hfA;

    prep_w_k<<<6192, 256, 0, stream>>>(dbw[0], dbw[1], dbw[2], dbw[3], dbw[4],
                                       c2_w, wb);
    c1_k<<<36, 256, 0, stream>>>(x, c1_w, c1_b, x0f, dbaA);

    for (int d = 0; d < 12; ++d) {
        unsigned short* hin  = (d & 1) ? dbaB : dbaA;
        unsigned short* hout = (d & 1) ? dbaA : dbaB;
        const float* featprev = (d < 3) ? x0f : featf;
        const unsigned short* wseg = wb + (size_t)d * 129024;
        const float* b1 = dbb[0] + (size_t)d * 16;
        const float* b2 = dbb[1] + (size_t)d * 16;
        const float* b3 = dbb[2] + (size_t)d * 16;
        const float* b4 = dbb[3] + (size_t)d * 16;
        const float* b5 = dbb[4] + (size_t)d * 64;
        int pos = d % 3;
        if (pos == 0)
            dense_block_k<<<288, 256, 0, stream>>>(hin, wseg, b1, b2, b3, b4, b5,
                0.2f, featprev, 1.f, nullptr, 0.f, hout, hfA);
        else if (pos == 1)
            dense_block_k<<<288, 256, 0, stream>>>(hin, wseg, b1, b2, b3, b4, b5,
                0.2f, hfA, 1.f, nullptr, 0.f, hout, hfB);
        else
            dense_block_k<<<288, 256, 0, stream>>>(hin, wseg, b1, b2, b3, b4, b5,
                0.04f, hfB, 0.2f, featprev, 1.f, hout, featf);
    }

    // c2: ff = conv(dbaA) + x0
    conv_mfma_k<<<288, 256, 0, stream>>>(dbaA, 64, 64, 64,
        wb + (size_t)12 * 129024, c2_b, 1.f, x0f, 1.f, ff);

    mlp_k<<<dim3(27, 3), 256, 0, stream>>>(fc1_w, fc1_b, fc2_w, fc2_b, WtT);
    dynfilter_k<<<dim3(3, 192), 256, 0, stream>>>(ff, WtT, (float*)d_out);
}

// Round 14
// 344.433 us; speedup vs baseline: 1.8673x; 1.5092x over previous
//
#include <hip/hip_runtime.h>

#define Hh 96
#define Ww 96
#define HW 9216
#define NPIX 589824   // 9216*64

typedef __attribute__((ext_vector_type(8))) short bf16x8;
typedef __attribute__((ext_vector_type(4))) float f32x4;

__device__ __forceinline__ unsigned short f2bf(float f) {
    unsigned int u = __float_as_uint(f);
    u += 0x7fff + ((u >> 16) & 1);          // RNE
    return (unsigned short)(u >> 16);
}

// ---------------------------------------------------------------------------
// Weight prep. Per-d segment (hw), rows PADDED for LDS bank-freedom (pad is
// baked into the GLOBAL layout because global_load_lds copies linearly and
// cannot write strided/padded destinations):
//  W1 @ 0      : [9*16][72]   (IC 64)    10368
//  W2 @ 10368  : [9*16][104]  (IC 80)    14976
//  W3 @ 25344  : [9*16][104]  (IC 96)    14976
//  W4 @ 40320  : [9*16][136]  (IC 112)   19584
//  W5 @ 59904  : [4 kq][9*64][40] (32ic) 92160
// per-d total 152064; c2 @ 12*152064 : [9][64][64] 36864 (global-read path)
// ---------------------------------------------------------------------------
__global__ __launch_bounds__(256) void prep_w_k(
    const float* __restrict__ w0, const float* __restrict__ w1,
    const float* __restrict__ w2, const float* __restrict__ w3,
    const float* __restrict__ w4, const float* __restrict__ c2w,
    unsigned short* __restrict__ wb)
{
    int idx = blockIdx.x * 256 + threadIdx.x;
    const int DSEG = 152064, TOT = 12 * 152064;
    if (idx >= TOT + 36864) return;
    float val;
    if (idx < TOT) {
        int d = idx / DSEG, rem = idx - d * DSEG;
        if (rem < 59904) {
            int e, L, IC; const float* wp;
            if      (rem < 10368) { e = rem;         L = 72;  IC = 64;  wp = w0; }
            else if (rem < 25344) { e = rem - 10368; L = 104; IC = 80;  wp = w1; }
            else if (rem < 40320) { e = rem - 25344; L = 104; IC = 96;  wp = w2; }
            else                  { e = rem - 40320; L = 136; IC = 112; wp = w3; }
            int row = e / L, col = e - row * L;
            int tap = row / 16, oc = row - tap * 16;
            val = (col < IC) ? wp[(((size_t)d * 16 + oc) * IC + col) * 9 + tap] : 0.f;
        } else {
            int e = rem - 59904;
            int kq = e / 23040, r = e - kq * 23040;
            int row = r / 40, col = r - row * 40;
            int tap = row / 64, oc = row - tap * 64;
            val = (col < 32)
                ? w4[(((size_t)d * 64 + oc) * 128 + kq * 32 + col) * 9 + tap] : 0.f;
        }
    } else {
        int e = idx - TOT;
        int tap = e / 4096, r = e & 4095;
        int oc = r >> 6, icp = r & 63;
        val = c2w[((size_t)(oc * 64 + icp)) * 9 + tap];
    }
    wb[idx] = f2bf(val);
}

// ---------------------------------------------------------------------------
// c1: 3->64 conv from NCHW fp32 x; writes x0f (fp32 NHWC) + dba (bf16 [9216][64])
// ---------------------------------------------------------------------------
__global__ __launch_bounds__(256) void c1_k(
    const float* __restrict__ x, const float* __restrict__ w,
    const float* __restrict__ bias,
    float* __restrict__ x0f, unsigned short* __restrict__ dba)
{
    __shared__ float sw[1728];
    __shared__ float sb[64];
    int tid = threadIdx.x;
    for (int i = tid; i < 1728; i += 256) sw[i] = w[i];
    if (tid < 64) sb[tid] = bias[tid];
    __syncthreads();
    int px = blockIdx.x * 256 + tid;
    int gy = px / 96, gx = px - (px / 96) * 96;
    float in[3][3][3];
    #pragma unroll
    for (int c = 0; c < 3; ++c)
        #pragma unroll
        for (int dy = 0; dy < 3; ++dy)
            #pragma unroll
            for (int dx = 0; dx < 3; ++dx) {
                int yy = gy - 1 + dy, xx = gx - 1 + dx;
                in[c][dy][dx] = (yy >= 0 && yy < 96 && xx >= 0 && xx < 96)
                                ? x[c * HW + yy * 96 + xx] : 0.f;
            }
    for (int oc = 0; oc < 64; ++oc) {
        float acc = sb[oc];
        const float* wp = &sw[oc * 27];
        #pragma unroll
        for (int c = 0; c < 3; ++c)
            #pragma unroll
            for (int dy = 0; dy < 3; ++dy)
                #pragma unroll
                for (int dx = 0; dx < 3; ++dx)
                    acc += wp[(c * 3 + dy) * 3 + dx] * in[c][dy][dx];
        x0f[(size_t)px * 64 + oc] = acc;
        dba[(size_t)px * 64 + oc] = f2bf(acc);
    }
}

// ---------------------------------------------------------------------------
// Fused dense block R14: 6x6 out tile -> grid 16x16 = 256 = EXACTLY 1
// block/CU (kills the 288-on-256 tail that set dispatch time = 2x single-
// block latency on 32 CUs). Halo 16x16 = 256 px (RSTR 16).
// Weights for s1-s4 and all 4 K-quarters of cv5 staged into LDS via
// global_load_lds (no VGPR cost), double-buffered slots; copy for stage k+1
// issued before stage k's compute; the vmcnt(0) drain at each __syncthreads
// guarantees arrival. All a-reads become bank-friendly LDS reads.
// LDS: act 256*136 + 2 slots * 23040 hw = 161792 B (1 block/CU - fine).
// ---------------------------------------------------------------------------
#define CSTR 136
#define RSTR 16
#define ACTHW 34816   // 256*136
#define SLOTHW 23040

__device__ __forceinline__ void gll_copy(const unsigned short* __restrict__ g,
                                         unsigned short* l, int nhw, int tid)
{
    for (int off = tid * 8; off < nhw; off += 2048)
        __builtin_amdgcn_global_load_lds(
            (const __attribute__((address_space(1))) void*)(g + off),
            (__attribute__((address_space(3))) void*)(l + off), 16, 0, 0);
}

template<int NS, int BS, int ICP, int ICPP, int OCH>
__device__ __forceinline__ void growth_stage(
    unsigned short* s, const unsigned short* wl,   // wl = LDS weight slot
    const float* __restrict__ bias, int wid, int l16, int q)
{
    constexpr int NPXr = NS * NS;
    constexpr int NT = (NPXr + 15) / 16;
    constexpr int MX = (NT + 3) / 4;
    f32x4 acc[MX];
    int lp0[MX], outp[MX];
    bool ok[MX];
    #pragma unroll
    for (int i = 0; i < MX; ++i) {
        int nt = wid + i * 4;
        int p  = nt * 16 + l16;
        bool live = (nt < NT) && (p < NPXr);
        ok[i] = live;
        int pc = live ? p : 0;            // clamp: reads stay in-bounds
        int r = pc / NS, c = pc - (pc / NS) * NS;
        lp0[i]  = (BS - 1 + r) * RSTR + (BS - 1 + c);
        outp[i] = (BS + r) * RSTR + (BS + c);
        acc[i]  = (f32x4){0.f, 0.f, 0.f, 0.f};
    }
    for (int kb = 0; kb < ICP; kb += 32) {
        #pragma unroll
        for (int tap = 0; tap < 9; ++tap) {
            const int dy = tap / 3, dx = tap - dy * 3;
            bf16x8 a = *(const bf16x8*)&wl[(tap * 16 + l16) * ICPP + kb + q * 8];
            #pragma unroll
            for (int i = 0; i < MX; ++i) {
                bf16x8 b = *(const bf16x8*)&s[(lp0[i] + dy * RSTR + dx) * CSTR + kb + q * 8];
                acc[i] = __builtin_amdgcn_mfma_f32_16x16x32_bf16(a, b, acc[i], 0, 0, 0);
            }
        }
    }
    const float4 bv = *(const float4*)&bias[q * 4];
    #pragma unroll
    for (int i = 0; i < MX; ++i) {
        if (!ok[i]) continue;
        float v0 = acc[i][0] + bv.x; v0 = v0 > 0.f ? v0 : 0.2f * v0;
        float v1 = acc[i][1] + bv.y; v1 = v1 > 0.f ? v1 : 0.2f * v1;
        float v2 = acc[i][2] + bv.z; v2 = v2 > 0.f ? v2 : 0.2f * v2;
        float v3 = acc[i][3] + bv.w; v3 = v3 > 0.f ? v3 : 0.2f * v3;
        ushort4 o = {f2bf(v0), f2bf(v1), f2bf(v2), f2bf(v3)};
        *(ushort4*)&s[outp[i] * CSTR + OCH + q * 4] = o;
    }
}

template<int KQ>
__device__ __forceinline__ void cv5_quarter(
    const unsigned short* s, const unsigned short* wl,
    int mt, int l16, int q, const int* lp0c, f32x4* acc)
{
    #pragma unroll
    for (int tap = 0; tap < 9; ++tap) {
        const int dy = tap / 3, dx = tap - dy * 3;
        bf16x8 a = *(const bf16x8*)&wl[(tap * 64 + mt * 16 + l16) * 40 + q * 8];
        #pragma unroll
        for (int nt = 0; nt < 3; ++nt) {
            bf16x8 b = *(const bf16x8*)&s[(lp0c[nt] + dy * RSTR + dx) * CSTR + KQ * 32 + q * 8];
            acc[nt] = __builtin_amdgcn_mfma_f32_16x16x32_bf16(a, b, acc[nt], 0, 0, 0);
        }
    }
}

__global__ __launch_bounds__(256) void dense_block_k(
    const unsigned short* __restrict__ hin,   // [9216][64] bf16
    const unsigned short* __restrict__ wb,    // this d's 152064-hw segment
    const float* __restrict__ b1, const float* __restrict__ b2,
    const float* __restrict__ b3, const float* __restrict__ b4,
    const float* __restrict__ b5,
    float alpha, const float* __restrict__ r1, float beta,
    const float* __restrict__ r2, float gamma,
    unsigned short* __restrict__ hout,        // [9216][64] bf16 (next h)
    float* out_fp)                            // fp32 NHWC [9216][64]
{
    const int tile = blockIdx.x;              // 0..255
    const int tx0 = (tile & 15) * 6, ty0 = (tile >> 4) * 6;
    const int tid = threadIdx.x;
    const int wid = tid >> 6, lane = tid & 63;
    const int l16 = lane & 15, q = lane >> 4;

    __shared__ unsigned short s[ACTHW + 2 * SLOTHW];   // 161792 B
    unsigned short* sA = s + ACTHW;
    unsigned short* sB = s + ACTHW + SLOTHW;

    gll_copy(wb, sA, 10368, tid);                       // W1 -> A

    // stage h into ch 0..63 (rows/cols ty0-5..+10); zero ch 64..127
    for (int i = tid; i < 256 * 16; i += 256) {
        int p = i >> 4, g = i & 15;
        int ly = p >> 4, lx = p & 15;
        int gy = ty0 - 5 + ly, gx = tx0 - 5 + lx;
        uint4 v = {0u, 0u, 0u, 0u};
        if (g < 8 && gy >= 0 && gy < 96 && gx >= 0 && gx < 96)
            v = *(const uint4*)&hin[(size_t)(gy * 96 + gx) * 64 + g * 8];
        *(uint4*)&s[p * CSTR + g * 8] = v;
    }
    __syncthreads();

    gll_copy(wb + 10368, sB, 14976, tid);               // W2 -> B
    growth_stage<14, 1,  64,  72,  64>(s, sA, b1, wid, l16, q);
    __syncthreads();

    gll_copy(wb + 25344, sA, 14976, tid);               // W3 -> A
    growth_stage<12, 2,  96, 104,  80>(s, sB, b2, wid, l16, q);
    __syncthreads();

    gll_copy(wb + 40320, sB, 19584, tid);               // W4 -> B
    growth_stage<10, 3,  96, 104,  96>(s, sA, b3, wid, l16, q);
    __syncthreads();

    gll_copy(wb + 59904, sA, 23040, tid);               // W5 q0 -> A
    growth_stage< 8, 4, 128, 136, 112>(s, sB, b4, wid, l16, q);
    __syncthreads();

    // cv5: OC=64, out 6x6 = 36 px; wave = mt (16 oc), 3 px-tiles (p<36
    // guarded), K accumulated over 4 LDS-staged quarters.
    // Output (ty0+row, tx0+col) window top-left = region (4+row, 4+col).
    {
        const int mt = wid;
        int lp0c[3];
        bool okc[3];
        int rowc[3], colc[3];
        #pragma unroll
        for (int nt = 0; nt < 3; ++nt) {
            int p = nt * 16 + l16;
            okc[nt] = (p < 36);
            int pc = okc[nt] ? p : 0;
            rowc[nt] = pc / 6; colc[nt] = pc - (pc / 6) * 6;
            lp0c[nt] = (4 + rowc[nt]) * RSTR + (4 + colc[nt]);
        }
        f32x4 acc[3];
        acc[0] = (f32x4){0.f,0.f,0.f,0.f};
        acc[1] = (f32x4){0.f,0.f,0.f,0.f};
        acc[2] = (f32x4){0.f,0.f,0.f,0.f};

        gll_copy(wb + 59904 + 23040, sB, 23040, tid);   // W5 q1 -> B
        cv5_quarter<0>(s, sA, mt, l16, q, lp0c, acc);
        __syncthreads();

        gll_copy(wb + 59904 + 2 * 23040, sA, 23040, tid); // W5 q2 -> A
        cv5_quarter<1>(s, sB, mt, l16, q, lp0c, acc);
        __syncthreads();

        gll_copy(wb + 59904 + 3 * 23040, sB, 23040, tid); // W5 q3 -> B
        cv5_quarter<2>(s, sA, mt, l16, q, lp0c, acc);
        __syncthreads();

        cv5_quarter<3>(s, sB, mt, l16, q, lp0c, acc);

        const float4 bv = *(const float4*)&b5[mt * 16 + q * 4];
        const int ocb = mt * 16 + q * 4;
        #pragma unroll
        for (int nt = 0; nt < 3; ++nt) {
            if (!okc[nt]) continue;
            size_t pix = (size_t)((ty0 + rowc[nt]) * 96 + tx0 + colc[nt]);
            float4 res1, res2;
            if (r1) res1 = *(const float4*)&r1[pix * 64 + ocb];
            if (r2) res2 = *(const float4*)&r2[pix * 64 + ocb];
            float vv[4];
            #pragma unroll
            for (int r = 0; r < 4; ++r) {
                float v = acc[nt][r] + ((const float*)&bv)[r];
                v *= alpha;
                if (r1) v += beta  * ((const float*)&res1)[r];
                if (r2) v += gamma * ((const float*)&res2)[r];
                vv[r] = v;
            }
            ushort4 o = {f2bf(vv[0]), f2bf(vv[1]), f2bf(vv[2]), f2bf(vv[3])};
            *(ushort4*)&hout[pix * 64 + ocb] = o;
            float4 of = {vv[0], vv[1], vv[2], vv[3]};
            *(float4*)&out_fp[pix * 64 + ocb] = of;
        }
    }
}

// ---------------------------------------------------------------------------
// MFMA 3x3 conv for c2 (64->64), 8x4 px tile, 288 blocks (global weights).
// ---------------------------------------------------------------------------
__global__ __launch_bounds__(256) void conv_mfma_k(
    const unsigned short* __restrict__ act, int cstride, int IC, int ICp,
    const unsigned short* __restrict__ wb,
    const float* __restrict__ bias,
    float alpha, const float* __restrict__ r1, float beta,
    float* __restrict__ out_fp)
{
    const int tile = blockIdx.x;             // 0..287
    const int tx0 = (tile % 12) * 8, ty0 = (tile / 12) * 4;
    const int tid = threadIdx.x;
    const int wid = tid >> 6, lane = tid & 63;
    const int l16 = lane & 15, q = lane >> 4;
    const int stride = ICp + 8;

    __shared__ unsigned short s[60 * 136];

    const int NG = ICp >> 3;
    for (int i = tid; i < 60 * NG; i += 256) {
        int hp = i / NG, g = i - hp * NG;
        int row = hp / 10, col = hp - row * 10;
        int gy = ty0 - 1 + row, gx = tx0 - 1 + col;
        int gc = g * 8;
        uint4 v = {0u, 0u, 0u, 0u};
        if (gy >= 0 && gy < 96 && gx >= 0 && gx < 96 && gc < IC)
            v = *reinterpret_cast<const uint4*>(
                    &act[(size_t)(gy * 96 + gx) * cstride + gc]);
        *reinterpret_cast<uint4*>(&s[hp * stride + gc]) = v;
    }
    __syncthreads();

    const int mt = wid;
    f32x4 acc0 = {0.f, 0.f, 0.f, 0.f}, acc1 = {0.f, 0.f, 0.f, 0.f};
    const int arow = (mt * 16 + l16) * ICp + q * 8;
    const int yy0 = l16 >> 3, xx0 = l16 & 7;
    const int yy1 = 2 + (l16 >> 3), xx1 = l16 & 7;
    for (int icb = 0; icb < ICp; icb += 32) {
        #pragma unroll
        for (int tap = 0; tap < 9; ++tap) {
            const int dy = tap / 3, dx = tap - dy * 3;
            bf16x8 a = *(const bf16x8*)&wb[(size_t)tap * 64 * ICp + arow + icb];
            bf16x8 b0 = *(const bf16x8*)&s[((yy0 + dy) * 10 + xx0 + dx) * stride + icb + q * 8];
            acc0 = __builtin_amdgcn_mfma_f32_16x16x32_bf16(a, b0, acc0, 0, 0, 0);
            bf16x8 b1 = *(const bf16x8*)&s[((yy1 + dy) * 10 + xx1 + dx) * stride + icb + q * 8];
            acc1 = __builtin_amdgcn_mfma_f32_16x16x32_bf16(a, b1, acc1, 0, 0, 0);
        }
    }
    const float4 bv = *(const float4*)&bias[mt * 16 + q * 4];
    #pragma unroll
    for (int nt = 0; nt < 2; ++nt) {
        f32x4 acc = nt ? acc1 : acc0;
        int p = nt * 16 + l16;
        size_t pix = (size_t)((ty0 + (p >> 3)) * 96 + tx0 + (p & 7));
        int ocb = mt * 16 + q * 4;
        float4 res1;
        if (r1) res1 = *(const float4*)&r1[pix * 64 + ocb];
        float4 o;
        #pragma unroll
        for (int r = 0; r < 4; ++r) {
            float v = acc[r] + ((const float*)&bv)[r];
            v *= alpha;
            if (r1) v += beta * ((const float*)&res1)[r];
            ((float*)&o)[r] = v;
        }
        *(float4*)&out_fp[pix * 64 + ocb] = o;
    }
}

// ---------------------------------------------------------------------------
// MLP: WtT[f][t] = fc2_b[f] + sum_j lrelu(a[j]*t + c[j]) * fc2_w[j][f]
// ---------------------------------------------------------------------------
__global__ __launch_bounds__(256) void mlp_k(
    const float* __restrict__ fc1_w, const float* __restrict__ fc1_b,
    const float* __restrict__ fc2_w, const float* __restrict__ fc2_b,
    float* __restrict__ WtT)
{
    const int f0 = blockIdx.x * 64, t0 = blockIdx.y * 64;
    const int tid = threadIdx.x;
    const int ft = tid & 15, tt = tid >> 4;
    __shared__ float sa[256], sc[256];
    __shared__ float swt[64][64];
    sa[tid] = fc1_w[tid] + fc1_w[256 + tid];
    sc[tid] = 2.f * fc1_w[512 + tid] + fc1_b[tid];
    float acc[4][4] = {};
    const float tbase = (float)(t0 + tt * 4);
    for (int jc = 0; jc < 256; jc += 64) {
        __syncthreads();
        for (int i = tid; i < 4096; i += 256) {
            int j = i >> 6, f = i & 63;
            swt[j][f] = fc2_w[(size_t)(jc + j) * 1728 + f0 + f];
        }
        __syncthreads();
        for (int j = 0; j < 64; ++j) {
            float4 wv = *(const float4*)&swt[j][ft * 4];
            float aj = sa[jc + j], cj = sc[jc + j];
            #pragma unroll
            for (int v = 0; v < 4; ++v) {
                float h = aj * (tbase + (float)v) + cj;
                h = (h > 0.f) ? h : 0.2f * h;
                acc[0][v] += h * wv.x;
                acc[1][v] += h * wv.y;
                acc[2][v] += h * wv.z;
                acc[3][v] += h * wv.w;
            }
        }
    }
    #pragma unroll
    for (int u = 0; u < 4; ++u) {
        int f = f0 + ft * 4 + u;
        float b = fc2_b[f];
        float4 o = {acc[u][0] + b, acc[u][1] + b, acc[u][2] + b, acc[u][3] + b};
        *(float4*)&WtT[(size_t)f * 192 + t0 + tt * 4] = o;
    }
}

// ---------------------------------------------------------------------------
// Final dynamic-filter gather; feat is fp32 NHWC [9216][64]
// ---------------------------------------------------------------------------
__global__ __launch_bounds__(256) void dynfilter_k(
    const float* __restrict__ feat,
    const float* __restrict__ WtT,
    float* __restrict__ out)
{
    const int h   = blockIdx.y;
    const int w0  = blockIdx.x * 64;
    const int tid = threadIdx.x;
    const int lw  = tid & 63, kc = tid >> 6;
    const int ybase = h / 2 - 1;
    const int x0lo  = w0 / 2 - 1;

    __shared__ float s_f[64][3][36];
    __shared__ float s_red[4][64];

    for (int i = tid; i < 64 * 102; i += 256) {
        int k = i & 63, j = i >> 6;
        int di = j / 34, col = j - di * 34;
        int yv = ybase + di, xv = x0lo + col;
        float v = 0.f;
        if (yv >= 0 && yv < Hh && xv >= 0 && xv < Ww)
            v = feat[(size_t)(yv * Ww + xv) * 64 + k];
        s_f[k][di][col] = v;
    }
    __syncthreads();

    const int w = w0 + lw;
    const int qq = w % 3;
    const int t = (h % 3) * 64 + w / 3;
    const int lx = (w / 2 - 1) - x0lo;
    const float* Wp = WtT + (size_t)(qq * 576 + kc * 144) * 192 + t;
    float acc = 0.f;
    for (int k = 0; k < 16; ++k) {
        #pragma unroll
        for (int di = 0; di < 3; ++di)
            #pragma unroll
            for (int dj = 0; dj < 3; ++dj)
                acc += s_f[kc * 16 + k][di][lx + dj]
                     * Wp[(size_t)(k * 9 + di * 3 + dj) * 192];
    }
    s_red[kc][lw] = acc;
    __syncthreads();
    if (kc == 0) {
        float v = s_red[0][lw] + s_red[1][lw] + s_red[2][lw] + s_red[3][lw];
        int o = h * 192 + w;
        out[o] = v;
        out[36864 + o] = v;
        out[2 * 36864 + o] = v;
    }
}

// ---------------------------------------------------------------------------
extern "C" void kernel_launch(void* const* d_in, const int* in_sizes, int n_in,
                              void* d_out, int out_size, void* d_ws, size_t ws_size,
                              hipStream_t stream)
{
    const float* x     = (const float*)d_in[0];
    const float* c1_w  = (const float*)d_in[1];
    const float* c1_b  = (const float*)d_in[2];
    const float* dbw[5] = {(const float*)d_in[3], (const float*)d_in[5],
                           (const float*)d_in[7], (const float*)d_in[9],
                           (const float*)d_in[11]};
    const float* dbb[5] = {(const float*)d_in[4], (const float*)d_in[6],
                           (const float*)d_in[8], (const float*)d_in[10],
                           (const float*)d_in[12]};
    const float* c2_w  = (const float*)d_in[13];
    const float* c2_b  = (const float*)d_in[14];
    const float* fc1_w = (const float*)d_in[15];
    const float* fc1_b = (const float*)d_in[16];
    const float* fc2_w = (const float*)d_in[17];
    const float* fc2_b = (const float*)d_in[18];

    float* ws    = (float*)d_ws;
    float* x0f   = ws;                    // [9216][64] fp32
    float* hfA   = ws + (size_t)NPIX;
    float* hfB   = ws + 2 * (size_t)NPIX;
    float* featf = ws + 3 * (size_t)NPIX;
    unsigned short* dbaA = (unsigned short*)(ws + 4 * (size_t)NPIX); // [9216][64] bf16
    unsigned short* dbaB = dbaA + (size_t)9216 * 64;
    unsigned short* wb   = dbaB + (size_t)9216 * 64;   // 12*152064 + 36864 hw
    float* WtT = (float*)(wb + (size_t)1861632 + 128); // 1728*192 f32
    float* ff  = hfA;

    prep_w_k<<<7272, 256, 0, stream>>>(dbw[0], dbw[1], dbw[2], dbw[3], dbw[4],
                                       c2_w, wb);
    c1_k<<<36, 256, 0, stream>>>(x, c1_w, c1_b, x0f, dbaA);

    for (int d = 0; d < 12; ++d) {
        unsigned short* hin  = (d & 1) ? dbaB : dbaA;
        unsigned short* hout = (d & 1) ? dbaA : dbaB;
        const float* featprev = (d < 3) ? x0f : featf;
        const unsigned short* wseg = wb + (size_t)d * 152064;
        const float* b1 = dbb[0] + (size_t)d * 16;
        const float* b2 = dbb[1] + (size_t)d * 16;
        const float* b3 = dbb[2] + (size_t)d * 16;
        const float* b4 = dbb[3] + (size_t)d * 16;
        const float* b5 = dbb[4] + (size_t)d * 64;
        int pos = d % 3;
        if (pos == 0)
            dense_block_k<<<256, 256, 0, stream>>>(hin, wseg, b1, b2, b3, b4, b5,
                0.2f, featprev, 1.f, nullptr, 0.f, hout, hfA);
        else if (pos == 1)
            dense_block_k<<<256, 256, 0, stream>>>(hin, wseg, b1, b2, b3, b4, b5,
                0.2f, hfA, 1.f, nullptr, 0.f, hout, hfB);
        else
            dense_block_k<<<256, 256, 0, stream>>>(hin, wseg, b1, b2, b3, b4, b5,
                0.04f, hfB, 0.2f, featprev, 1.f, hout, featf);
    }

    // c2: ff = conv(dbaA) + x0
    conv_mfma_k<<<288, 256, 0, stream>>>(dbaA, 64, 64, 64,
        wb + (size_t)12 * 152064, c2_b, 1.f, x0f, 1.f, ff);

    mlp_k<<<dim3(27, 3), 256, 0, stream>>>(fc1_w, fc1_b, fc2_w, fc2_b, WtT);
    dynfilter_k<<<dim3(3, 192), 256, 0, stream>>>(ff, WtT, (float*)d_out);
}

// Round 15
// 341.029 us; speedup vs baseline: 1.8860x; 1.0100x over previous
//
#include <hip/hip_runtime.h>

#define Hh 96
#define Ww 96
#define HW 9216
#define NPIX 589824   // 9216*64

typedef __attribute__((ext_vector_type(8))) short bf16x8;
typedef __attribute__((ext_vector_type(4))) float f32x4;

__device__ __forceinline__ unsigned short f2bf(float f) {
    unsigned int u = __float_as_uint(f);
    u += 0x7fff + ((u >> 16) & 1);          // RNE
    return (unsigned short)(u >> 16);
}

// ---------------------------------------------------------------------------
// Weight prep. Per-d segment (hw), rows PADDED for LDS bank-freedom (pad is
// baked into the GLOBAL layout because global_load_lds copies linearly):
//  W1 @ 0      : [9*16][72]   (IC 64)    10368
//  W2 @ 10368  : [9*16][104]  (IC 80)    14976
//  W3 @ 25344  : [9*16][104]  (IC 96)    14976
//  W4 @ 40320  : [9*16][136]  (IC 112)   19584
//  W5 @ 59904  : [4 kq][9*64][40] (32ic) 92160
// per-d total 152064; c2 @ 12*152064 : [2 kh][9*64][40] (32ic) 46080
// ---------------------------------------------------------------------------
__global__ __launch_bounds__(256) void prep_w_k(
    const float* __restrict__ w0, const float* __restrict__ w1,
    const float* __restrict__ w2, const float* __restrict__ w3,
    const float* __restrict__ w4, const float* __restrict__ c2w,
    unsigned short* __restrict__ wb)
{
    int idx = blockIdx.x * 256 + threadIdx.x;
    const int DSEG = 152064, TOT = 12 * 152064;
    if (idx >= TOT + 46080) return;
    float val;
    if (idx < TOT) {
        int d = idx / DSEG, rem = idx - d * DSEG;
        if (rem < 59904) {
            int e, L, IC; const float* wp;
            if      (rem < 10368) { e = rem;         L = 72;  IC = 64;  wp = w0; }
            else if (rem < 25344) { e = rem - 10368; L = 104; IC = 80;  wp = w1; }
            else if (rem < 40320) { e = rem - 25344; L = 104; IC = 96;  wp = w2; }
            else                  { e = rem - 40320; L = 136; IC = 112; wp = w3; }
            int row = e / L, col = e - row * L;
            int tap = row / 16, oc = row - tap * 16;
            val = (col < IC) ? wp[(((size_t)d * 16 + oc) * IC + col) * 9 + tap] : 0.f;
        } else {
            int e = rem - 59904;
            int kq = e / 23040, r = e - kq * 23040;
            int row = r / 40, col = r - row * 40;
            int tap = row / 64, oc = row - tap * 64;
            val = (col < 32)
                ? w4[(((size_t)d * 64 + oc) * 128 + kq * 32 + col) * 9 + tap] : 0.f;
        }
    } else {
        int e = idx - TOT;                   // 0..46079
        int kh = e / 23040, r = e - kh * 23040;
        int row = r / 40, col = r - row * 40;
        int tap = row / 64, oc = row - tap * 64;
        val = (col < 32)
            ? c2w[((size_t)(oc * 64) + kh * 32 + col) * 9 + tap] : 0.f;
    }
    wb[idx] = f2bf(val);
}

// ---------------------------------------------------------------------------
// c1: 3->64 conv from NCHW fp32 x; writes x0f (fp32 NHWC) + dba (bf16 [9216][64])
// ---------------------------------------------------------------------------
__global__ __launch_bounds__(256) void c1_k(
    const float* __restrict__ x, const float* __restrict__ w,
    const float* __restrict__ bias,
    float* __restrict__ x0f, unsigned short* __restrict__ dba)
{
    __shared__ float sw[1728];
    __shared__ float sb[64];
    int tid = threadIdx.x;
    for (int i = tid; i < 1728; i += 256) sw[i] = w[i];
    if (tid < 64) sb[tid] = bias[tid];
    __syncthreads();
    int px = blockIdx.x * 256 + tid;
    int gy = px / 96, gx = px - (px / 96) * 96;
    float in[3][3][3];
    #pragma unroll
    for (int c = 0; c < 3; ++c)
        #pragma unroll
        for (int dy = 0; dy < 3; ++dy)
            #pragma unroll
            for (int dx = 0; dx < 3; ++dx) {
                int yy = gy - 1 + dy, xx = gx - 1 + dx;
                in[c][dy][dx] = (yy >= 0 && yy < 96 && xx >= 0 && xx < 96)
                                ? x[c * HW + yy * 96 + xx] : 0.f;
            }
    for (int oc = 0; oc < 64; ++oc) {
        float acc = sb[oc];
        const float* wp = &sw[oc * 27];
        #pragma unroll
        for (int c = 0; c < 3; ++c)
            #pragma unroll
            for (int dy = 0; dy < 3; ++dy)
                #pragma unroll
                for (int dx = 0; dx < 3; ++dx)
                    acc += wp[(c * 3 + dy) * 3 + dx] * in[c][dy][dx];
        x0f[(size_t)px * 64 + oc] = acc;
        dba[(size_t)px * 64 + oc] = f2bf(acc);
    }
}

// ---------------------------------------------------------------------------
// Fused dense block R14 (unchanged): 6x6 out tile, grid 256 = 1 block/CU,
// halo 16x16, weights LDS-staged via global_load_lds, double-buffered.
// ---------------------------------------------------------------------------
#define CSTR 136
#define RSTR 16
#define ACTHW 34816   // 256*136
#define SLOTHW 23040

__device__ __forceinline__ void gll_copy(const unsigned short* __restrict__ g,
                                         unsigned short* l, int nhw, int tid)
{
    for (int off = tid * 8; off < nhw; off += 2048)
        __builtin_amdgcn_global_load_lds(
            (const __attribute__((address_space(1))) void*)(g + off),
            (__attribute__((address_space(3))) void*)(l + off), 16, 0, 0);
}

template<int NS, int BS, int ICP, int ICPP, int OCH>
__device__ __forceinline__ void growth_stage(
    unsigned short* s, const unsigned short* wl,   // wl = LDS weight slot
    const float* __restrict__ bias, int wid, int l16, int q)
{
    constexpr int NPXr = NS * NS;
    constexpr int NT = (NPXr + 15) / 16;
    constexpr int MX = (NT + 3) / 4;
    f32x4 acc[MX];
    int lp0[MX], outp[MX];
    bool ok[MX];
    #pragma unroll
    for (int i = 0; i < MX; ++i) {
        int nt = wid + i * 4;
        int p  = nt * 16 + l16;
        bool live = (nt < NT) && (p < NPXr);
        ok[i] = live;
        int pc = live ? p : 0;            // clamp: reads stay in-bounds
        int r = pc / NS, c = pc - (pc / NS) * NS;
        lp0[i]  = (BS - 1 + r) * RSTR + (BS - 1 + c);
        outp[i] = (BS + r) * RSTR + (BS + c);
        acc[i]  = (f32x4){0.f, 0.f, 0.f, 0.f};
    }
    for (int kb = 0; kb < ICP; kb += 32) {
        #pragma unroll
        for (int tap = 0; tap < 9; ++tap) {
            const int dy = tap / 3, dx = tap - dy * 3;
            bf16x8 a = *(const bf16x8*)&wl[(tap * 16 + l16) * ICPP + kb + q * 8];
            #pragma unroll
            for (int i = 0; i < MX; ++i) {
                bf16x8 b = *(const bf16x8*)&s[(lp0[i] + dy * RSTR + dx) * CSTR + kb + q * 8];
                acc[i] = __builtin_amdgcn_mfma_f32_16x16x32_bf16(a, b, acc[i], 0, 0, 0);
            }
        }
    }
    const float4 bv = *(const float4*)&bias[q * 4];
    #pragma unroll
    for (int i = 0; i < MX; ++i) {
        if (!ok[i]) continue;
        float v0 = acc[i][0] + bv.x; v0 = v0 > 0.f ? v0 : 0.2f * v0;
        float v1 = acc[i][1] + bv.y; v1 = v1 > 0.f ? v1 : 0.2f * v1;
        float v2 = acc[i][2] + bv.z; v2 = v2 > 0.f ? v2 : 0.2f * v2;
        float v3 = acc[i][3] + bv.w; v3 = v3 > 0.f ? v3 : 0.2f * v3;
        ushort4 o = {f2bf(v0), f2bf(v1), f2bf(v2), f2bf(v3)};
        *(ushort4*)&s[outp[i] * CSTR + OCH + q * 4] = o;
    }
}

template<int KQ>
__device__ __forceinline__ void cv5_quarter(
    const unsigned short* s, const unsigned short* wl,
    int mt, int l16, int q, const int* lp0c, f32x4* acc)
{
    #pragma unroll
    for (int tap = 0; tap < 9; ++tap) {
        const int dy = tap / 3, dx = tap - dy * 3;
        bf16x8 a = *(const bf16x8*)&wl[(tap * 64 + mt * 16 + l16) * 40 + q * 8];
        #pragma unroll
        for (int nt = 0; nt < 3; ++nt) {
            bf16x8 b = *(const bf16x8*)&s[(lp0c[nt] + dy * RSTR + dx) * CSTR + KQ * 32 + q * 8];
            acc[nt] = __builtin_amdgcn_mfma_f32_16x16x32_bf16(a, b, acc[nt], 0, 0, 0);
        }
    }
}

__global__ __launch_bounds__(256) void dense_block_k(
    const unsigned short* __restrict__ hin,   // [9216][64] bf16
    const unsigned short* __restrict__ wb,    // this d's 152064-hw segment
    const float* __restrict__ b1, const float* __restrict__ b2,
    const float* __restrict__ b3, const float* __restrict__ b4,
    const float* __restrict__ b5,
    float alpha, const float* __restrict__ r1, float beta,
    const float* __restrict__ r2, float gamma,
    unsigned short* __restrict__ hout,        // [9216][64] bf16 (next h)
    float* out_fp)                            // fp32 NHWC [9216][64]
{
    const int tile = blockIdx.x;              // 0..255
    const int tx0 = (tile & 15) * 6, ty0 = (tile >> 4) * 6;
    const int tid = threadIdx.x;
    const int wid = tid >> 6, lane = tid & 63;
    const int l16 = lane & 15, q = lane >> 4;

    __shared__ unsigned short s[ACTHW + 2 * SLOTHW];   // 161792 B
    unsigned short* sA = s + ACTHW;
    unsigned short* sB = s + ACTHW + SLOTHW;

    gll_copy(wb, sA, 10368, tid);                       // W1 -> A

    // stage h into ch 0..63 (rows/cols ty0-5..+10); zero ch 64..127
    for (int i = tid; i < 256 * 16; i += 256) {
        int p = i >> 4, g = i & 15;
        int ly = p >> 4, lx = p & 15;
        int gy = ty0 - 5 + ly, gx = tx0 - 5 + lx;
        uint4 v = {0u, 0u, 0u, 0u};
        if (g < 8 && gy >= 0 && gy < 96 && gx >= 0 && gx < 96)
            v = *(const uint4*)&hin[(size_t)(gy * 96 + gx) * 64 + g * 8];
        *(uint4*)&s[p * CSTR + g * 8] = v;
    }
    __syncthreads();

    gll_copy(wb + 10368, sB, 14976, tid);               // W2 -> B
    growth_stage<14, 1,  64,  72,  64>(s, sA, b1, wid, l16, q);
    __syncthreads();

    gll_copy(wb + 25344, sA, 14976, tid);               // W3 -> A
    growth_stage<12, 2,  96, 104,  80>(s, sB, b2, wid, l16, q);
    __syncthreads();

    gll_copy(wb + 40320, sB, 19584, tid);               // W4 -> B
    growth_stage<10, 3,  96, 104,  96>(s, sA, b3, wid, l16, q);
    __syncthreads();

    gll_copy(wb + 59904, sA, 23040, tid);               // W5 q0 -> A
    growth_stage< 8, 4, 128, 136, 112>(s, sB, b4, wid, l16, q);
    __syncthreads();

    // cv5: OC=64, out 6x6 = 36 px; wave = mt (16 oc), 3 px-tiles,
    // K accumulated over 4 LDS-staged quarters.
    {
        const int mt = wid;
        int lp0c[3];
        bool okc[3];
        int rowc[3], colc[3];
        #pragma unroll
        for (int nt = 0; nt < 3; ++nt) {
            int p = nt * 16 + l16;
            okc[nt] = (p < 36);
            int pc = okc[nt] ? p : 0;
            rowc[nt] = pc / 6; colc[nt] = pc - (pc / 6) * 6;
            lp0c[nt] = (4 + rowc[nt]) * RSTR + (4 + colc[nt]);
        }
        f32x4 acc[3];
        acc[0] = (f32x4){0.f,0.f,0.f,0.f};
        acc[1] = (f32x4){0.f,0.f,0.f,0.f};
        acc[2] = (f32x4){0.f,0.f,0.f,0.f};

        gll_copy(wb + 59904 + 23040, sB, 23040, tid);   // W5 q1 -> B
        cv5_quarter<0>(s, sA, mt, l16, q, lp0c, acc);
        __syncthreads();

        gll_copy(wb + 59904 + 2 * 23040, sA, 23040, tid); // W5 q2 -> A
        cv5_quarter<1>(s, sB, mt, l16, q, lp0c, acc);
        __syncthreads();

        gll_copy(wb + 59904 + 3 * 23040, sB, 23040, tid); // W5 q3 -> B
        cv5_quarter<2>(s, sA, mt, l16, q, lp0c, acc);
        __syncthreads();

        cv5_quarter<3>(s, sB, mt, l16, q, lp0c, acc);

        const float4 bv = *(const float4*)&b5[mt * 16 + q * 4];
        const int ocb = mt * 16 + q * 4;
        #pragma unroll
        for (int nt = 0; nt < 3; ++nt) {
            if (!okc[nt]) continue;
            size_t pix = (size_t)((ty0 + rowc[nt]) * 96 + tx0 + colc[nt]);
            float4 res1, res2;
            if (r1) res1 = *(const float4*)&r1[pix * 64 + ocb];
            if (r2) res2 = *(const float4*)&r2[pix * 64 + ocb];
            float vv[4];
            #pragma unroll
            for (int r = 0; r < 4; ++r) {
                float v = acc[nt][r] + ((const float*)&bv)[r];
                v *= alpha;
                if (r1) v += beta  * ((const float*)&res1)[r];
                if (r2) v += gamma * ((const float*)&res2)[r];
                vv[r] = v;
            }
            ushort4 o = {f2bf(vv[0]), f2bf(vv[1]), f2bf(vv[2]), f2bf(vv[3])};
            *(ushort4*)&hout[pix * 64 + ocb] = o;
            float4 of = {vv[0], vv[1], vv[2], vv[3]};
            *(float4*)&out_fp[pix * 64 + ocb] = of;
        }
    }
}

// ---------------------------------------------------------------------------
// c2 (64->64) R15: 6x6 tile, grid 256 (tail-free, like dense), weights
// LDS-staged in 2 K-halves via global_load_lds (layout [2][9*64][40]).
// Act halo 8x8 x 64ch, stride 72 (bank-clean). ff = conv + x0.
// ---------------------------------------------------------------------------
__global__ __launch_bounds__(256) void c2_mfma6_k(
    const unsigned short* __restrict__ act,   // [9216][64] bf16
    const unsigned short* __restrict__ wb2,   // [2][576][40]
    const float* __restrict__ bias,
    const float* __restrict__ r1,             // x0f
    float* __restrict__ out_fp)               // ff
{
    const int tile = blockIdx.x;              // 0..255
    const int tx0 = (tile & 15) * 6, ty0 = (tile >> 4) * 6;
    const int tid = threadIdx.x;
    const int wid = tid >> 6, lane = tid & 63;
    const int l16 = lane & 15, q = lane >> 4;
    const int mt  = wid;

    __shared__ unsigned short s[64 * 72 + 2 * SLOTHW];  // 101376 B
    unsigned short* sA = s + 64 * 72;
    unsigned short* sB = sA + SLOTHW;

    gll_copy(wb2, sA, 23040, tid);            // kh0 weights -> A

    // stage act halo 8x8 (rows/cols ty0-1..+6), 64 ch, stride 72
    for (int i = tid; i < 64 * 8; i += 256) {
        int p = i >> 3, g = i & 7;
        int ly = p >> 3, lx = p & 7;
        int gy = ty0 - 1 + ly, gx = tx0 - 1 + lx;
        uint4 v = {0u, 0u, 0u, 0u};
        if (gy >= 0 && gy < 96 && gx >= 0 && gx < 96)
            v = *(const uint4*)&act[(size_t)(gy * 96 + gx) * 64 + g * 8];
        *(uint4*)&s[p * 72 + g * 8] = v;
    }
    __syncthreads();

    gll_copy(wb2 + SLOTHW, sB, 23040, tid);   // kh1 weights -> B

    int lp0c[3];
    bool okc[3];
    int rowc[3], colc[3];
    #pragma unroll
    for (int nt = 0; nt < 3; ++nt) {
        int p = nt * 16 + l16;
        okc[nt] = (p < 36);
        int pc = okc[nt] ? p : 0;
        rowc[nt] = pc / 6; colc[nt] = pc - (pc / 6) * 6;
        lp0c[nt] = rowc[nt] * 8 + colc[nt];   // window top-left in 8x8 halo
    }
    f32x4 acc[3];
    acc[0] = (f32x4){0.f,0.f,0.f,0.f};
    acc[1] = (f32x4){0.f,0.f,0.f,0.f};
    acc[2] = (f32x4){0.f,0.f,0.f,0.f};

    // kh0 from sA (act ch 0..31)
    #pragma unroll
    for (int tap = 0; tap < 9; ++tap) {
        const int dy = tap / 3, dx = tap - dy * 3;
        bf16x8 a = *(const bf16x8*)&sA[(tap * 64 + mt * 16 + l16) * 40 + q * 8];
        #pragma unroll
        for (int nt = 0; nt < 3; ++nt) {
            bf16x8 b = *(const bf16x8*)&s[(lp0c[nt] + dy * 8 + dx) * 72 + q * 8];
            acc[nt] = __builtin_amdgcn_mfma_f32_16x16x32_bf16(a, b, acc[nt], 0, 0, 0);
        }
    }
    __syncthreads();   // vmcnt(0) drain: sB ready

    // kh1 from sB (act ch 32..63)
    #pragma unroll
    for (int tap = 0; tap < 9; ++tap) {
        const int dy = tap / 3, dx = tap - dy * 3;
        bf16x8 a = *(const bf16x8*)&sB[(tap * 64 + mt * 16 + l16) * 40 + q * 8];
        #pragma unroll
        for (int nt = 0; nt < 3; ++nt) {
            bf16x8 b = *(const bf16x8*)&s[(lp0c[nt] + dy * 8 + dx) * 72 + 32 + q * 8];
            acc[nt] = __builtin_amdgcn_mfma_f32_16x16x32_bf16(a, b, acc[nt], 0, 0, 0);
        }
    }

    const float4 bv = *(const float4*)&bias[mt * 16 + q * 4];
    const int ocb = mt * 16 + q * 4;
    #pragma unroll
    for (int nt = 0; nt < 3; ++nt) {
        if (!okc[nt]) continue;
        size_t pix = (size_t)((ty0 + rowc[nt]) * 96 + tx0 + colc[nt]);
        float4 res1 = *(const float4*)&r1[pix * 64 + ocb];
        float4 o;
        #pragma unroll
        for (int r = 0; r < 4; ++r)
            ((float*)&o)[r] = acc[nt][r] + ((const float*)&bv)[r]
                              + ((const float*)&res1)[r];
        *(float4*)&out_fp[pix * 64 + ocb] = o;
    }
}

// ---------------------------------------------------------------------------
// MLP: WtT[f][t] = fc2_b[f] + sum_j lrelu(a[j]*t + c[j]) * fc2_w[j][f]
// ---------------------------------------------------------------------------
__global__ __launch_bounds__(256) void mlp_k(
    const float* __restrict__ fc1_w, const float* __restrict__ fc1_b,
    const float* __restrict__ fc2_w, const float* __restrict__ fc2_b,
    float* __restrict__ WtT)
{
    const int f0 = blockIdx.x * 64, t0 = blockIdx.y * 64;
    const int tid = threadIdx.x;
    const int ft = tid & 15, tt = tid >> 4;
    __shared__ float sa[256], sc[256];
    __shared__ float swt[64][64];
    sa[tid] = fc1_w[tid] + fc1_w[256 + tid];
    sc[tid] = 2.f * fc1_w[512 + tid] + fc1_b[tid];
    float acc[4][4] = {};
    const float tbase = (float)(t0 + tt * 4);
    for (int jc = 0; jc < 256; jc += 64) {
        __syncthreads();
        for (int i = tid; i < 4096; i += 256) {
            int j = i >> 6, f = i & 63;
            swt[j][f] = fc2_w[(size_t)(jc + j) * 1728 + f0 + f];
        }
        __syncthreads();
        for (int j = 0; j < 64; ++j) {
            float4 wv = *(const float4*)&swt[j][ft * 4];
            float aj = sa[jc + j], cj = sc[jc + j];
            #pragma unroll
            for (int v = 0; v < 4; ++v) {
                float h = aj * (tbase + (float)v) + cj;
                h = (h > 0.f) ? h : 0.2f * h;
                acc[0][v] += h * wv.x;
                acc[1][v] += h * wv.y;
                acc[2][v] += h * wv.z;
                acc[3][v] += h * wv.w;
            }
        }
    }
    #pragma unroll
    for (int u = 0; u < 4; ++u) {
        int f = f0 + ft * 4 + u;
        float b = fc2_b[f];
        float4 o = {acc[u][0] + b, acc[u][1] + b, acc[u][2] + b, acc[u][3] + b};
        *(float4*)&WtT[(size_t)f * 192 + t0 + tt * 4] = o;
    }
}

// ---------------------------------------------------------------------------
// Final dynamic-filter gather; feat is fp32 NHWC [9216][64]
// ---------------------------------------------------------------------------
__global__ __launch_bounds__(256) void dynfilter_k(
    const float* __restrict__ feat,
    const float* __restrict__ WtT,
    float* __restrict__ out)
{
    const int h   = blockIdx.y;
    const int w0  = blockIdx.x * 64;
    const int tid = threadIdx.x;
    const int lw  = tid & 63, kc = tid >> 6;
    const int ybase = h / 2 - 1;
    const int x0lo  = w0 / 2 - 1;

    __shared__ float s_f[64][3][36];
    __shared__ float s_red[4][64];

    for (int i = tid; i < 64 * 102; i += 256) {
        int k = i & 63, j = i >> 6;
        int di = j / 34, col = j - di * 34;
        int yv = ybase + di, xv = x0lo + col;
        float v = 0.f;
        if (yv >= 0 && yv < Hh && xv >= 0 && xv < Ww)
            v = feat[(size_t)(yv * Ww + xv) * 64 + k];
        s_f[k][di][col] = v;
    }
    __syncthreads();

    const int w = w0 + lw;
    const int qq = w % 3;
    const int t = (h % 3) * 64 + w / 3;
    const int lx = (w / 2 - 1) - x0lo;
    const float* Wp = WtT + (size_t)(qq * 576 + kc * 144) * 192 + t;
    float acc = 0.f;
    for (int k = 0; k < 16; ++k) {
        #pragma unroll
        for (int di = 0; di < 3; ++di)
            #pragma unroll
            for (int dj = 0; dj < 3; ++dj)
                acc += s_f[kc * 16 + k][di][lx + dj]
                     * Wp[(size_t)(k * 9 + di * 3 + dj) * 192];
    }
    s_red[kc][lw] = acc;
    __syncthreads();
    if (kc == 0) {
        float v = s_red[0][lw] + s_red[1][lw] + s_red[2][lw] + s_red[3][lw];
        int o = h * 192 + w;
        out[o] = v;
        out[36864 + o] = v;
        out[2 * 36864 + o] = v;
    }
}

// ---------------------------------------------------------------------------
extern "C" void kernel_launch(void* const* d_in, const int* in_sizes, int n_in,
                              void* d_out, int out_size, void* d_ws, size_t ws_size,
                              hipStream_t stream)
{
    const float* x     = (const float*)d_in[0];
    const float* c1_w  = (const float*)d_in[1];
    const float* c1_b  = (const float*)d_in[2];
    const float* dbw[5] = {(const float*)d_in[3], (const float*)d_in[5],
                           (const float*)d_in[7], (const float*)d_in[9],
                           (const float*)d_in[11]};
    const float* dbb[5] = {(const float*)d_in[4], (const float*)d_in[6],
                           (const float*)d_in[8], (const float*)d_in[10],
                           (const float*)d_in[12]};
    const float* c2_w  = (const float*)d_in[13];
    const float* c2_b  = (const float*)d_in[14];
    const float* fc1_w = (const float*)d_in[15];
    const float* fc1_b = (const float*)d_in[16];
    const float* fc2_w = (const float*)d_in[17];
    const float* fc2_b = (const float*)d_in[18];

    float* ws    = (float*)d_ws;
    float* x0f   = ws;                    // [9216][64] fp32
    float* hfA   = ws + (size_t)NPIX;
    float* hfB   = ws + 2 * (size_t)NPIX;
    float* featf = ws + 3 * (size_t)NPIX;
    unsigned short* dbaA = (unsigned short*)(ws + 4 * (size_t)NPIX); // [9216][64] bf16
    unsigned short* dbaB = dbaA + (size_t)9216 * 64;
    unsigned short* wb   = dbaB + (size_t)9216 * 64;   // 12*152064 + 46080 hw
    float* WtT = (float*)(wb + (size_t)1870848 + 128); // 1728*192 f32
    float* ff  = hfA;

    prep_w_k<<<7308, 256, 0, stream>>>(dbw[0], dbw[1], dbw[2], dbw[3], dbw[4],
                                       c2_w, wb);
    c1_k<<<36, 256, 0, stream>>>(x, c1_w, c1_b, x0f, dbaA);

    for (int d = 0; d < 12; ++d) {
        unsigned short* hin  = (d & 1) ? dbaB : dbaA;
        unsigned short* hout = (d & 1) ? dbaA : dbaB;
        const float* featprev = (d < 3) ? x0f : featf;
        const unsigned short* wseg = wb + (size_t)d * 152064;
        const float* b1 = dbb[0] + (size_t)d * 16;
        const float* b2 = dbb[1] + (size_t)d * 16;
        const float* b3 = dbb[2] + (size_t)d * 16;
        const float* b4 = dbb[3] + (size_t)d * 16;
        const float* b5 = dbb[4] + (size_t)d * 64;
        int pos = d % 3;
        if (pos == 0)
            dense_block_k<<<256, 256, 0, stream>>>(hin, wseg, b1, b2, b3, b4, b5,
                0.2f, featprev, 1.f, nullptr, 0.f, hout, hfA);
        else if (pos == 1)
            dense_block_k<<<256, 256, 0, stream>>>(hin, wseg, b1, b2, b3, b4, b5,
                0.2f, hfA, 1.f, nullptr, 0.f, hout, hfB);
        else
            dense_block_k<<<256, 256, 0, stream>>>(hin, wseg, b1, b2, b3, b4, b5,
                0.04f, hfB, 0.2f, featprev, 1.f, hout, featf);
    }

    // c2: ff = conv(dbaA) + x0  (d=11 wrote dbaA)
    c2_mfma6_k<<<256, 256, 0, stream>>>(dbaA, wb + (size_t)12 * 152064,
                                        c2_b, x0f, ff);

    mlp_k<<<dim3(27, 3), 256, 0, stream>>>(fc1_w, fc1_b, fc2_w, fc2_b, WtT);
    dynfilter_k<<<dim3(3, 192), 256, 0, stream>>>(ff, WtT, (float*)d_out);
}

// Round 16
// 340.911 us; speedup vs baseline: 1.8866x; 1.0003x over previous
//
#include <hip/hip_runtime.h>

#define Hh 96
#define Ww 96
#define HW 9216
#define NPIX 589824   // 9216*64

typedef __attribute__((ext_vector_type(8))) short bf16x8;
typedef __attribute__((ext_vector_type(4))) float f32x4;

__device__ __forceinline__ unsigned short f2bf(float f) {
    unsigned int u = __float_as_uint(f);
    u += 0x7fff + ((u >> 16) & 1);          // RNE
    return (unsigned short)(u >> 16);
}

// ---------------------------------------------------------------------------
// Weight prep. Per-d segment (hw), rows PADDED for LDS bank-freedom (pad is
// baked into the GLOBAL layout because global_load_lds copies linearly):
//  W1 @ 0      : [9*16][72]   (IC 64)    10368
//  W2 @ 10368  : [9*16][104]  (IC 80)    14976
//  W3 @ 25344  : [9*16][104]  (IC 96)    14976
//  W4 @ 40320  : [9*16][136]  (IC 112)   19584
//  W5 @ 59904  : [4 kq][9*64][40] (32ic) 92160
// per-d total 152064; c2 @ 12*152064 : [2 kh][9*64][40] (32ic) 46080
// ---------------------------------------------------------------------------
__global__ __launch_bounds__(256) void prep_w_k(
    const float* __restrict__ w0, const float* __restrict__ w1,
    const float* __restrict__ w2, const float* __restrict__ w3,
    const float* __restrict__ w4, const float* __restrict__ c2w,
    unsigned short* __restrict__ wb)
{
    int idx = blockIdx.x * 256 + threadIdx.x;
    const int DSEG = 152064, TOT = 12 * 152064;
    if (idx >= TOT + 46080) return;
    float val;
    if (idx < TOT) {
        int d = idx / DSEG, rem = idx - d * DSEG;
        if (rem < 59904) {
            int e, L, IC; const float* wp;
            if      (rem < 10368) { e = rem;         L = 72;  IC = 64;  wp = w0; }
            else if (rem < 25344) { e = rem - 10368; L = 104; IC = 80;  wp = w1; }
            else if (rem < 40320) { e = rem - 25344; L = 104; IC = 96;  wp = w2; }
            else                  { e = rem - 40320; L = 136; IC = 112; wp = w3; }
            int row = e / L, col = e - row * L;
            int tap = row / 16, oc = row - tap * 16;
            val = (col < IC) ? wp[(((size_t)d * 16 + oc) * IC + col) * 9 + tap] : 0.f;
        } else {
            int e = rem - 59904;
            int kq = e / 23040, r = e - kq * 23040;
            int row = r / 40, col = r - row * 40;
            int tap = row / 64, oc = row - tap * 64;
            val = (col < 32)
                ? w4[(((size_t)d * 64 + oc) * 128 + kq * 32 + col) * 9 + tap] : 0.f;
        }
    } else {
        int e = idx - TOT;                   // 0..46079
        int kh = e / 23040, r = e - kh * 23040;
        int row = r / 40, col = r - row * 40;
        int tap = row / 64, oc = row - tap * 64;
        val = (col < 32)
            ? c2w[((size_t)(oc * 64) + kh * 32 + col) * 9 + tap] : 0.f;
    }
    wb[idx] = f2bf(val);
}

// ---------------------------------------------------------------------------
// c1: 3->64 conv from NCHW fp32 x; writes x0f (fp32 NHWC) + dba (bf16 [9216][64])
// ---------------------------------------------------------------------------
__global__ __launch_bounds__(256) void c1_k(
    const float* __restrict__ x, const float* __restrict__ w,
    const float* __restrict__ bias,
    float* __restrict__ x0f, unsigned short* __restrict__ dba)
{
    __shared__ float sw[1728];
    __shared__ float sb[64];
    int tid = threadIdx.x;
    for (int i = tid; i < 1728; i += 256) sw[i] = w[i];
    if (tid < 64) sb[tid] = bias[tid];
    __syncthreads();
    int px = blockIdx.x * 256 + tid;
    int gy = px / 96, gx = px - (px / 96) * 96;
    float in[3][3][3];
    #pragma unroll
    for (int c = 0; c < 3; ++c)
        #pragma unroll
        for (int dy = 0; dy < 3; ++dy)
            #pragma unroll
            for (int dx = 0; dx < 3; ++dx) {
                int yy = gy - 1 + dy, xx = gx - 1 + dx;
                in[c][dy][dx] = (yy >= 0 && yy < 96 && xx >= 0 && xx < 96)
                                ? x[c * HW + yy * 96 + xx] : 0.f;
            }
    for (int oc = 0; oc < 64; ++oc) {
        float acc = sb[oc];
        const float* wp = &sw[oc * 27];
        #pragma unroll
        for (int c = 0; c < 3; ++c)
            #pragma unroll
            for (int dy = 0; dy < 3; ++dy)
                #pragma unroll
                for (int dx = 0; dx < 3; ++dx)
                    acc += wp[(c * 3 + dy) * 3 + dx] * in[c][dy][dx];
        x0f[(size_t)px * 64 + oc] = acc;
        dba[(size_t)px * 64 + oc] = f2bf(acc);
    }
}

// ---------------------------------------------------------------------------
// Fused dense block R14 (unchanged): 6x6 out tile, grid 256 = 1 block/CU,
// halo 16x16, weights LDS-staged via global_load_lds, double-buffered.
// ---------------------------------------------------------------------------
#define CSTR 136
#define RSTR 16
#define ACTHW 34816   // 256*136
#define SLOTHW 23040

__device__ __forceinline__ void gll_copy(const unsigned short* __restrict__ g,
                                         unsigned short* l, int nhw, int tid)
{
    for (int off = tid * 8; off < nhw; off += 2048)
        __builtin_amdgcn_global_load_lds(
            (const __attribute__((address_space(1))) void*)(g + off),
            (__attribute__((address_space(3))) void*)(l + off), 16, 0, 0);
}

template<int NS, int BS, int ICP, int ICPP, int OCH>
__device__ __forceinline__ void growth_stage(
    unsigned short* s, const unsigned short* wl,   // wl = LDS weight slot
    const float* __restrict__ bias, int wid, int l16, int q)
{
    constexpr int NPXr = NS * NS;
    constexpr int NT = (NPXr + 15) / 16;
    constexpr int MX = (NT + 3) / 4;
    f32x4 acc[MX];
    int lp0[MX], outp[MX];
    bool ok[MX];
    #pragma unroll
    for (int i = 0; i < MX; ++i) {
        int nt = wid + i * 4;
        int p  = nt * 16 + l16;
        bool live = (nt < NT) && (p < NPXr);
        ok[i] = live;
        int pc = live ? p : 0;            // clamp: reads stay in-bounds
        int r = pc / NS, c = pc - (pc / NS) * NS;
        lp0[i]  = (BS - 1 + r) * RSTR + (BS - 1 + c);
        outp[i] = (BS + r) * RSTR + (BS + c);
        acc[i]  = (f32x4){0.f, 0.f, 0.f, 0.f};
    }
    for (int kb = 0; kb < ICP; kb += 32) {
        #pragma unroll
        for (int tap = 0; tap < 9; ++tap) {
            const int dy = tap / 3, dx = tap - dy * 3;
            bf16x8 a = *(const bf16x8*)&wl[(tap * 16 + l16) * ICPP + kb + q * 8];
            #pragma unroll
            for (int i = 0; i < MX; ++i) {
                bf16x8 b = *(const bf16x8*)&s[(lp0[i] + dy * RSTR + dx) * CSTR + kb + q * 8];
                acc[i] = __builtin_amdgcn_mfma_f32_16x16x32_bf16(a, b, acc[i], 0, 0, 0);
            }
        }
    }
    const float4 bv = *(const float4*)&bias[q * 4];
    #pragma unroll
    for (int i = 0; i < MX; ++i) {
        if (!ok[i]) continue;
        float v0 = acc[i][0] + bv.x; v0 = v0 > 0.f ? v0 : 0.2f * v0;
        float v1 = acc[i][1] + bv.y; v1 = v1 > 0.f ? v1 : 0.2f * v1;
        float v2 = acc[i][2] + bv.z; v2 = v2 > 0.f ? v2 : 0.2f * v2;
        float v3 = acc[i][3] + bv.w; v3 = v3 > 0.f ? v3 : 0.2f * v3;
        ushort4 o = {f2bf(v0), f2bf(v1), f2bf(v2), f2bf(v3)};
        *(ushort4*)&s[outp[i] * CSTR + OCH + q * 4] = o;
    }
}

template<int KQ>
__device__ __forceinline__ void cv5_quarter(
    const unsigned short* s, const unsigned short* wl,
    int mt, int l16, int q, const int* lp0c, f32x4* acc)
{
    #pragma unroll
    for (int tap = 0; tap < 9; ++tap) {
        const int dy = tap / 3, dx = tap - dy * 3;
        bf16x8 a = *(const bf16x8*)&wl[(tap * 64 + mt * 16 + l16) * 40 + q * 8];
        #pragma unroll
        for (int nt = 0; nt < 3; ++nt) {
            bf16x8 b = *(const bf16x8*)&s[(lp0c[nt] + dy * RSTR + dx) * CSTR + KQ * 32 + q * 8];
            acc[nt] = __builtin_amdgcn_mfma_f32_16x16x32_bf16(a, b, acc[nt], 0, 0, 0);
        }
    }
}

__global__ __launch_bounds__(256) void dense_block_k(
    const unsigned short* __restrict__ hin,   // [9216][64] bf16
    const unsigned short* __restrict__ wb,    // this d's 152064-hw segment
    const float* __restrict__ b1, const float* __restrict__ b2,
    const float* __restrict__ b3, const float* __restrict__ b4,
    const float* __restrict__ b5,
    float alpha, const float* __restrict__ r1, float beta,
    const float* __restrict__ r2, float gamma,
    unsigned short* __restrict__ hout,        // [9216][64] bf16 (next h)
    float* out_fp)                            // fp32 NHWC [9216][64]
{
    const int tile = blockIdx.x;              // 0..255
    const int tx0 = (tile & 15) * 6, ty0 = (tile >> 4) * 6;
    const int tid = threadIdx.x;
    const int wid = tid >> 6, lane = tid & 63;
    const int l16 = lane & 15, q = lane >> 4;

    __shared__ unsigned short s[ACTHW + 2 * SLOTHW];   // 161792 B
    unsigned short* sA = s + ACTHW;
    unsigned short* sB = s + ACTHW + SLOTHW;

    gll_copy(wb, sA, 10368, tid);                       // W1 -> A

    // stage h into ch 0..63 (rows/cols ty0-5..+10); zero ch 64..127
    for (int i = tid; i < 256 * 16; i += 256) {
        int p = i >> 4, g = i & 15;
        int ly = p >> 4, lx = p & 15;
        int gy = ty0 - 5 + ly, gx = tx0 - 5 + lx;
        uint4 v = {0u, 0u, 0u, 0u};
        if (g < 8 && gy >= 0 && gy < 96 && gx >= 0 && gx < 96)
            v = *(const uint4*)&hin[(size_t)(gy * 96 + gx) * 64 + g * 8];
        *(uint4*)&s[p * CSTR + g * 8] = v;
    }
    __syncthreads();

    gll_copy(wb + 10368, sB, 14976, tid);               // W2 -> B
    growth_stage<14, 1,  64,  72,  64>(s, sA, b1, wid, l16, q);
    __syncthreads();

    gll_copy(wb + 25344, sA, 14976, tid);               // W3 -> A
    growth_stage<12, 2,  96, 104,  80>(s, sB, b2, wid, l16, q);
    __syncthreads();

    gll_copy(wb + 40320, sB, 19584, tid);               // W4 -> B
    growth_stage<10, 3,  96, 104,  96>(s, sA, b3, wid, l16, q);
    __syncthreads();

    gll_copy(wb + 59904, sA, 23040, tid);               // W5 q0 -> A
    growth_stage< 8, 4, 128, 136, 112>(s, sB, b4, wid, l16, q);
    __syncthreads();

    // cv5: OC=64, out 6x6 = 36 px; wave = mt (16 oc), 3 px-tiles,
    // K accumulated over 4 LDS-staged quarters.
    {
        const int mt = wid;
        int lp0c[3];
        bool okc[3];
        int rowc[3], colc[3];
        #pragma unroll
        for (int nt = 0; nt < 3; ++nt) {
            int p = nt * 16 + l16;
            okc[nt] = (p < 36);
            int pc = okc[nt] ? p : 0;
            rowc[nt] = pc / 6; colc[nt] = pc - (pc / 6) * 6;
            lp0c[nt] = (4 + rowc[nt]) * RSTR + (4 + colc[nt]);
        }
        f32x4 acc[3];
        acc[0] = (f32x4){0.f,0.f,0.f,0.f};
        acc[1] = (f32x4){0.f,0.f,0.f,0.f};
        acc[2] = (f32x4){0.f,0.f,0.f,0.f};

        gll_copy(wb + 59904 + 23040, sB, 23040, tid);   // W5 q1 -> B
        cv5_quarter<0>(s, sA, mt, l16, q, lp0c, acc);
        __syncthreads();

        gll_copy(wb + 59904 + 2 * 23040, sA, 23040, tid); // W5 q2 -> A
        cv5_quarter<1>(s, sB, mt, l16, q, lp0c, acc);
        __syncthreads();

        gll_copy(wb + 59904 + 3 * 23040, sB, 23040, tid); // W5 q3 -> B
        cv5_quarter<2>(s, sA, mt, l16, q, lp0c, acc);
        __syncthreads();

        cv5_quarter<3>(s, sB, mt, l16, q, lp0c, acc);

        const float4 bv = *(const float4*)&b5[mt * 16 + q * 4];
        const int ocb = mt * 16 + q * 4;
        #pragma unroll
        for (int nt = 0; nt < 3; ++nt) {
            if (!okc[nt]) continue;
            size_t pix = (size_t)((ty0 + rowc[nt]) * 96 + tx0 + colc[nt]);
            float4 res1, res2;
            if (r1) res1 = *(const float4*)&r1[pix * 64 + ocb];
            if (r2) res2 = *(const float4*)&r2[pix * 64 + ocb];
            float vv[4];
            #pragma unroll
            for (int r = 0; r < 4; ++r) {
                float v = acc[nt][r] + ((const float*)&bv)[r];
                v *= alpha;
                if (r1) v += beta  * ((const float*)&res1)[r];
                if (r2) v += gamma * ((const float*)&res2)[r];
                vv[r] = v;
            }
            ushort4 o = {f2bf(vv[0]), f2bf(vv[1]), f2bf(vv[2]), f2bf(vv[3])};
            *(ushort4*)&hout[pix * 64 + ocb] = o;
            float4 of = {vv[0], vv[1], vv[2], vv[3]};
            *(float4*)&out_fp[pix * 64 + ocb] = of;
        }
    }
}

// ---------------------------------------------------------------------------
// c2 (64->64) R15: 6x6 tile, grid 256 (tail-free, like dense), weights
// LDS-staged in 2 K-halves via global_load_lds (layout [2][9*64][40]).
// Act halo 8x8 x 64ch, stride 72 (bank-clean). ff = conv + x0.
// ---------------------------------------------------------------------------
__global__ __launch_bounds__(256) void c2_mfma6_k(
    const unsigned short* __restrict__ act,   // [9216][64] bf16
    const unsigned short* __restrict__ wb2,   // [2][576][40]
    const float* __restrict__ bias,
    const float* __restrict__ r1,             // x0f
    float* __restrict__ out_fp)               // ff
{
    const int tile = blockIdx.x;              // 0..255
    const int tx0 = (tile & 15) * 6, ty0 = (tile >> 4) * 6;
    const int tid = threadIdx.x;
    const int wid = tid >> 6, lane = tid & 63;
    const int l16 = lane & 15, q = lane >> 4;
    const int mt  = wid;

    __shared__ unsigned short s[64 * 72 + 2 * SLOTHW];  // 101376 B
    unsigned short* sA = s + 64 * 72;
    unsigned short* sB = sA + SLOTHW;

    gll_copy(wb2, sA, 23040, tid);            // kh0 weights -> A

    // stage act halo 8x8 (rows/cols ty0-1..+6), 64 ch, stride 72
    for (int i = tid; i < 64 * 8; i += 256) {
        int p = i >> 3, g = i & 7;
        int ly = p >> 3, lx = p & 7;
        int gy = ty0 - 1 + ly, gx = tx0 - 1 + lx;
        uint4 v = {0u, 0u, 0u, 0u};
        if (gy >= 0 && gy < 96 && gx >= 0 && gx < 96)
            v = *(const uint4*)&act[(size_t)(gy * 96 + gx) * 64 + g * 8];
        *(uint4*)&s[p * 72 + g * 8] = v;
    }
    __syncthreads();

    gll_copy(wb2 + SLOTHW, sB, 23040, tid);   // kh1 weights -> B

    int lp0c[3];
    bool okc[3];
    int rowc[3], colc[3];
    #pragma unroll
    for (int nt = 0; nt < 3; ++nt) {
        int p = nt * 16 + l16;
        okc[nt] = (p < 36);
        int pc = okc[nt] ? p : 0;
        rowc[nt] = pc / 6; colc[nt] = pc - (pc / 6) * 6;
        lp0c[nt] = rowc[nt] * 8 + colc[nt];   // window top-left in 8x8 halo
    }
    f32x4 acc[3];
    acc[0] = (f32x4){0.f,0.f,0.f,0.f};
    acc[1] = (f32x4){0.f,0.f,0.f,0.f};
    acc[2] = (f32x4){0.f,0.f,0.f,0.f};

    // kh0 from sA (act ch 0..31)
    #pragma unroll
    for (int tap = 0; tap < 9; ++tap) {
        const int dy = tap / 3, dx = tap - dy * 3;
        bf16x8 a = *(const bf16x8*)&sA[(tap * 64 + mt * 16 + l16) * 40 + q * 8];
        #pragma unroll
        for (int nt = 0; nt < 3; ++nt) {
            bf16x8 b = *(const bf16x8*)&s[(lp0c[nt] + dy * 8 + dx) * 72 + q * 8];
            acc[nt] = __builtin_amdgcn_mfma_f32_16x16x32_bf16(a, b, acc[nt], 0, 0, 0);
        }
    }
    __syncthreads();   // vmcnt(0) drain: sB ready

    // kh1 from sB (act ch 32..63)
    #pragma unroll
    for (int tap = 0; tap < 9; ++tap) {
        const int dy = tap / 3, dx = tap - dy * 3;
        bf16x8 a = *(const bf16x8*)&sB[(tap * 64 + mt * 16 + l16) * 40 + q * 8];
        #pragma unroll
        for (int nt = 0; nt < 3; ++nt) {
            bf16x8 b = *(const bf16x8*)&s[(lp0c[nt] + dy * 8 + dx) * 72 + 32 + q * 8];
            acc[nt] = __builtin_amdgcn_mfma_f32_16x16x32_bf16(a, b, acc[nt], 0, 0, 0);
        }
    }

    const float4 bv = *(const float4*)&bias[mt * 16 + q * 4];
    const int ocb = mt * 16 + q * 4;
    #pragma unroll
    for (int nt = 0; nt < 3; ++nt) {
        if (!okc[nt]) continue;
        size_t pix = (size_t)((ty0 + rowc[nt]) * 96 + tx0 + colc[nt]);
        float4 res1 = *(const float4*)&r1[pix * 64 + ocb];
        float4 o;
        #pragma unroll
        for (int r = 0; r < 4; ++r)
            ((float*)&o)[r] = acc[nt][r] + ((const float*)&bv)[r]
                              + ((const float*)&res1)[r];
        *(float4*)&out_fp[pix * 64 + ocb] = o;
    }
}

// ---------------------------------------------------------------------------
// MLP: WtT[f][t] = fc2_b[f] + sum_j lrelu(a[j]*t + c[j]) * fc2_w[j][f]
// ---------------------------------------------------------------------------
__global__ __launch_bounds__(256) void mlp_k(
    const float* __restrict__ fc1_w, const float* __restrict__ fc1_b,
    const float* __restrict__ fc2_w, const float* __restrict__ fc2_b,
    float* __restrict__ WtT)
{
    const int f0 = blockIdx.x * 64, t0 = blockIdx.y * 64;
    const int tid = threadIdx.x;
    const int ft = tid & 15, tt = tid >> 4;
    __shared__ float sa[256], sc[256];
    __shared__ float swt[64][64];
    sa[tid] = fc1_w[tid] + fc1_w[256 + tid];
    sc[tid] = 2.f * fc1_w[512 + tid] + fc1_b[tid];
    float acc[4][4] = {};
    const float tbase = (float)(t0 + tt * 4);
    for (int jc = 0; jc < 256; jc += 64) {
        __syncthreads();
        for (int i = tid; i < 4096; i += 256) {
            int j = i >> 6, f = i & 63;
            swt[j][f] = fc2_w[(size_t)(jc + j) * 1728 + f0 + f];
        }
        __syncthreads();
        for (int j = 0; j < 64; ++j) {
            float4 wv = *(const float4*)&swt[j][ft * 4];
            float aj = sa[jc + j], cj = sc[jc + j];
            #pragma unroll
            for (int v = 0; v < 4; ++v) {
                float h = aj * (tbase + (float)v) + cj;
                h = (h > 0.f) ? h : 0.2f * h;
                acc[0][v] += h * wv.x;
                acc[1][v] += h * wv.y;
                acc[2][v] += h * wv.z;
                acc[3][v] += h * wv.w;
            }
        }
    }
    #pragma unroll
    for (int u = 0; u < 4; ++u) {
        int f = f0 + ft * 4 + u;
        float b = fc2_b[f];
        float4 o = {acc[u][0] + b, acc[u][1] + b, acc[u][2] + b, acc[u][3] + b};
        *(float4*)&WtT[(size_t)f * 192 + t0 + tt * 4] = o;
    }
}

// ---------------------------------------------------------------------------
// Final dynamic-filter gather; feat is fp32 NHWC [9216][64]
// ---------------------------------------------------------------------------
__global__ __launch_bounds__(256) void dynfilter_k(
    const float* __restrict__ feat,
    const float* __restrict__ WtT,
    float* __restrict__ out)
{
    const int h   = blockIdx.y;
    const int w0  = blockIdx.x * 64;
    const int tid = threadIdx.x;
    const int lw  = tid & 63, kc = tid >> 6;
    const int ybase = h / 2 - 1;
    const int x0lo  = w0 / 2 - 1;

    __shared__ float s_f[64][3][36];
    __shared__ float s_red[4][64];

    for (int i = tid; i < 64 * 102; i += 256) {
        int k = i & 63, j = i >> 6;
        int di = j / 34, col = j - di * 34;
        int yv = ybase + di, xv = x0lo + col;
        float v = 0.f;
        if (yv >= 0 && yv < Hh && xv >= 0 && xv < Ww)
            v = feat[(size_t)(yv * Ww + xv) * 64 + k];
        s_f[k][di][col] = v;
    }
    __syncthreads();

    const int w = w0 + lw;
    const int qq = w % 3;
    const int t = (h % 3) * 64 + w / 3;
    const int lx = (w / 2 - 1) - x0lo;
    const float* Wp = WtT + (size_t)(qq * 576 + kc * 144) * 192 + t;
    float acc = 0.f;
    for (int k = 0; k < 16; ++k) {
        #pragma unroll
        for (int di = 0; di < 3; ++di)
            #pragma unroll
            for (int dj = 0; dj < 3; ++dj)
                acc += s_f[kc * 16 + k][di][lx + dj]
                     * Wp[(size_t)(k * 9 + di * 3 + dj) * 192];
    }
    s_red[kc][lw] = acc;
    __syncthreads();
    if (kc == 0) {
        float v = s_red[0][lw] + s_red[1][lw] + s_red[2][lw] + s_red[3][lw];
        int o = h * 192 + w;
        out[o] = v;
        out[36864 + o] = v;
        out[2 * 36864 + o] = v;
    }
}

// ---------------------------------------------------------------------------
extern "C" void kernel_launch(void* const* d_in, const int* in_sizes, int n_in,
                              void* d_out, int out_size, void* d_ws, size_t ws_size,
                              hipStream_t stream)
{
    const float* x     = (const float*)d_in[0];
    const float* c1_w  = (const float*)d_in[1];
    const float* c1_b  = (const float*)d_in[2];
    const float* dbw[5] = {(const float*)d_in[3], (const float*)d_in[5],
                           (const float*)d_in[7], (const float*)d_in[9],
                           (const float*)d_in[11]};
    const float* dbb[5] = {(const float*)d_in[4], (const float*)d_in[6],
                           (const float*)d_in[8], (const float*)d_in[10],
                           (const float*)d_in[12]};
    const float* c2_w  = (const float*)d_in[13];
    const float* c2_b  = (const float*)d_in[14];
    const float* fc1_w = (const float*)d_in[15];
    const float* fc1_b = (const float*)d_in[16];
    const float* fc2_w = (const float*)d_in[17];
    const float* fc2_b = (const float*)d_in[18];

    float* ws    = (float*)d_ws;
    float* x0f   = ws;                    // [9216][64] fp32
    float* hfA   = ws + (size_t)NPIX;
    float* hfB   = ws + 2 * (size_t)NPIX;
    float* featf = ws + 3 * (size_t)NPIX;
    unsigned short* dbaA = (unsigned short*)(ws + 4 * (size_t)NPIX); // [9216][64] bf16
    unsigned short* dbaB = dbaA + (size_t)9216 * 64;
    unsigned short* wb   = dbaB + (size_t)9216 * 64;   // 12*152064 + 46080 hw
    float* WtT = (float*)(wb + (size_t)1870848 + 128); // 1728*192 f32
    float* ff  = hfA;

    prep_w_k<<<7308, 256, 0, stream>>>(dbw[0], dbw[1], dbw[2], dbw[3], dbw[4],
                                       c2_w, wb);
    c1_k<<<36, 256, 0, stream>>>(x, c1_w, c1_b, x0f, dbaA);

    for (int d = 0; d < 12; ++d) {
        unsigned short* hin  = (d & 1) ? dbaB : dbaA;
        unsigned short* hout = (d & 1) ? dbaA : dbaB;
        const float* featprev = (d < 3) ? x0f : featf;
        const unsigned short* wseg = wb + (size_t)d * 152064;
        const float* b1 = dbb[0] + (size_t)d * 16;
        const float* b2 = dbb[1] + (size_t)d * 16;
        const float* b3 = dbb[2] + (size_t)d * 16;
        const float* b4 = dbb[3] + (size_t)d * 16;
        const float* b5 = dbb[4] + (size_t)d * 64;
        int pos = d % 3;
        if (pos == 0)
            dense_block_k<<<256, 256, 0, stream>>>(hin, wseg, b1, b2, b3, b4, b5,
                0.2f, featprev, 1.f, nullptr, 0.f, hout, hfA);
        else if (pos == 1)
            dense_block_k<<<256, 256, 0, stream>>>(hin, wseg, b1, b2, b3, b4, b5,
                0.2f, hfA, 1.f, nullptr, 0.f, hout, hfB);
        else
            dense_block_k<<<256, 256, 0, stream>>>(hin, wseg, b1, b2, b3, b4, b5,
                0.04f, hfB, 0.2f, featprev, 1.f, hout, featf);
    }

    // c2: ff = conv(dbaA) + x0  (d=11 wrote dbaA)
    c2_mfma6_k<<<256, 256, 0, stream>>>(dbaA, wb + (size_t)12 * 152064,
                                        c2_b, x0f, ff);

    mlp_k<<<dim3(27, 3), 256, 0, stream>>>(fc1_w, fc1_b, fc2_w, fc2_b, WtT);
    dynfilter_k<<<dim3(3, 192), 256, 0, stream>>>(ff, WtT, (float*)d_out);
}